// Round 3
// baseline (5381.397 us; speedup 1.0000x reference)
//
#include <hip/hip_runtime.h>
#include <math.h>

#define EPS 1e-6f

constexpr int BSZ = 16;    // batch * S
constexpr int DD  = 512;   // channels / S
constexpr int NN  = 4096;  // H*W
constexpr int RR  = 64;
constexpr int STEPS = 7;
constexpr int NS_B  = 8;   // BtB d-split blocks
constexpr int NS_C  = 32;  // CtC n-split blocks
constexpr int NS_N2 = 8;   // numer2 n-split partials

__device__ __forceinline__ void fma4s(float4& a, const float4& b, float s) {
  a.x = fmaf(b.x, s, a.x); a.y = fmaf(b.y, s, a.y);
  a.z = fmaf(b.z, s, a.z); a.w = fmaf(b.w, s, a.w);
}

// ---------------- Gram partials: outp[split][b][k][lane] = sum_rows M[row][k]*M[row][lane]
__global__ void __launch_bounds__(256) gram_kernel(const float* __restrict__ M,
                                                   float* __restrict__ outp,
                                                   int rowsPerWave,
                                                   long long batchStride) {
  __shared__ float red[RR * RR];
  const int lane = threadIdx.x & 63;
  const int wid  = threadIdx.x >> 6;
  const int b    = blockIdx.y;
  const long long rowbase = (long long)(blockIdx.x * 4 + wid) * rowsPerWave;
  const float* Mp = M + (long long)b * batchStride + rowbase * RR;
  float acc[RR];
  #pragma unroll
  for (int k = 0; k < RR; ++k) acc[k] = 0.f;
  #pragma unroll 2
  for (int rr = 0; rr < rowsPerWave; ++rr) {
    const float v = Mp[(long long)rr * RR + lane];
    #pragma unroll
    for (int k = 0; k < RR; ++k) acc[k] = fmaf(__shfl(v, k), v, acc[k]);
  }
  for (int w = 0; w < 4; ++w) {
    if (wid == w) {
      if (w == 0) {
        #pragma unroll
        for (int k = 0; k < RR; ++k) red[k * RR + lane] = acc[k];
      } else {
        #pragma unroll
        for (int k = 0; k < RR; ++k) red[k * RR + lane] += acc[k];
      }
    }
    __syncthreads();
  }
  float* op = outp + ((long long)blockIdx.x * BSZ + b) * (RR * RR);
  for (int i = threadIdx.x; i < RR * RR; i += 256) op[i] = red[i];
}

// ---------------- sum nsplit partials of 4096 floats per batch
__global__ void __launch_bounds__(256) reduce_kernel(const float* __restrict__ src,
                                                     float* __restrict__ dst,
                                                     int nsplit) {
  const int b  = blockIdx.x;
  const int i0 = threadIdx.x * 16;
  float4 a0 = make_float4(0,0,0,0), a1 = a0, a2 = a0, a3 = a0;
  for (int s = 0; s < nsplit; ++s) {
    const float4* p = (const float4*)&src[((long long)s * BSZ + b) * 4096 + i0];
    a0.x += p[0].x; a0.y += p[0].y; a0.z += p[0].z; a0.w += p[0].w;
    a1.x += p[1].x; a1.y += p[1].y; a1.z += p[1].z; a1.w += p[1].w;
    a2.x += p[2].x; a2.y += p[2].y; a2.z += p[2].z; a2.w += p[2].w;
    a3.x += p[3].x; a3.y += p[3].y; a3.z += p[3].z; a3.w += p[3].w;
  }
  float4* o = (float4*)&dst[(long long)b * 4096 + i0];
  o[0] = a0; o[1] = a1; o[2] = a2; o[3] = a3;
}

// ---------------- coef kernel: MODE0 softmax-init, MODE1 multiplicative update.
// grid (NN/128, BSZ), block 256 = 4 waves: wave = (h = wid>>1, nsub = wid&1).
// Lane owns one n; accumulates r-half (32) in regs; B rows via wave-uniform s_loads.
template <int MODE>
__global__ void __launch_bounds__(256) coef_kernel(const float* __restrict__ X,
                                                   const float* __restrict__ Bw,
                                                   const float* __restrict__ btb,
                                                   float* __restrict__ coef) {
  const int b    = blockIdx.y;
  const int wid  = threadIdx.x >> 6;
  const int lane = threadIdx.x & 63;
  const int nsub = wid & 1;
  const int h    = wid >> 1;
  const int n    = (blockIdx.x << 7) + (nsub << 6) + lane;

  const float*  xptr = X + (long long)b * DD * NN + n;
  const float4* bp4  = (const float4*)(Bw + (long long)b * DD * RR) + (h << 3);

  float4 acc[8];
  #pragma unroll
  for (int q = 0; q < 8; ++q) acc[q] = make_float4(0,0,0,0);

  #pragma unroll 4
  for (int d = 0; d < DD; ++d) {
    const float xv = xptr[(long long)d * NN];
    const float4* br = bp4 + d * 16;   // wave-uniform -> s_load
    #pragma unroll
    for (int q = 0; q < 8; ++q) fma4s(acc[q], br[q], xv);
  }

  if constexpr (MODE == 0) {
    __shared__ float sm[128][68];
    const int lrow = (nsub << 6) + lane;
    #pragma unroll
    for (int q = 0; q < 8; ++q)
      *(float4*)&sm[lrow][(h << 5) + (q << 2)] = acc[q];
    __syncthreads();
    float4 row[16];
    #pragma unroll
    for (int q = 0; q < 16; ++q) row[q] = *(const float4*)&sm[lrow][q << 2];
    float m = -1e30f;
    #pragma unroll
    for (int q = 0; q < 16; ++q)
      m = fmaxf(m, fmaxf(fmaxf(row[q].x, row[q].y), fmaxf(row[q].z, row[q].w)));
    float ssum = 0.f;
    #pragma unroll
    for (int q = 0; q < 16; ++q) {
      row[q].x = __expf(row[q].x - m); row[q].y = __expf(row[q].y - m);
      row[q].z = __expf(row[q].z - m); row[q].w = __expf(row[q].w - m);
      ssum += row[q].x + row[q].y + row[q].z + row[q].w;
    }
    const float inv = 1.f / ssum;
    float4* cp = (float4*)(coef + ((long long)b * NN + n) * RR + (h << 5));
    #pragma unroll
    for (int q = 0; q < 8; ++q) {
      float4 e = row[(h << 3) + q];
      e.x *= inv; e.y *= inv; e.z *= inv; e.w *= inv;
      cp[q] = e;
    }
  } else {
    // denom = coef_old(row n) @ BtB(:, r-half)
    const float*  btbS  = btb + (long long)b * 4096 + (h << 5);
    const float4* coldp = (const float4*)(coef + ((long long)b * NN + n) * RR);
    // snapshot own half of the OLD coef row before anyone writes
    float4 coldh[8];
    #pragma unroll
    for (int q = 0; q < 8; ++q) coldh[q] = coldp[(h << 3) + q];
    float4 dn[8];
    #pragma unroll
    for (int q = 0; q < 8; ++q) dn[q] = make_float4(0,0,0,0);
    for (int q = 0; q < 16; ++q) {          // k-groups of 4 over the OLD row
      const float4 c4 = coldp[q];
      const float4* t0 = (const float4*)(btbS + (4 * q + 0) * RR);
      const float4* t1 = (const float4*)(btbS + (4 * q + 1) * RR);
      const float4* t2 = (const float4*)(btbS + (4 * q + 2) * RR);
      const float4* t3 = (const float4*)(btbS + (4 * q + 3) * RR);
      #pragma unroll
      for (int j = 0; j < 8; ++j) {
        fma4s(dn[j], t0[j], c4.x); fma4s(dn[j], t1[j], c4.y);
        fma4s(dn[j], t2[j], c4.z); fma4s(dn[j], t3[j], c4.w);
      }
    }
    // all old-coef reads done; wait for the sibling wave (other r-half, same n)
    __syncthreads();
    float4* cp = (float4*)(coef + ((long long)b * NN + n) * RR + (h << 5));
    #pragma unroll
    for (int q = 0; q < 8; ++q) {
      const float4 co = coldh[q];
      float4 o;
      o.x = co.x * acc[q].x / (dn[q].x + EPS);
      o.y = co.y * acc[q].y / (dn[q].y + EPS);
      o.z = co.z * acc[q].z / (dn[q].z + EPS);
      o.w = co.w * acc[q].w / (dn[q].w + EPS);
      cp[q] = o;
    }
  }
}

// ---------------- numer2 partials: n2p[s][b][d][r] = sum_{n in slice} x[d][n]*coef[n][r]
__global__ void __launch_bounds__(256) numer2_kernel(const float* __restrict__ X,
                                                     const float* __restrict__ coef,
                                                     float* __restrict__ n2p) {
  __shared__ float xs[128 * 65];
  const int b    = blockIdx.z;
  const int s    = blockIdx.y;
  const int d0   = blockIdx.x << 7;
  const int wid  = threadIdx.x >> 6;
  const int lane = threadIdx.x & 63;
  const int dsub = wid & 1;
  const int h    = wid >> 1;
  const int nbeg = s * (NN / NS_N2);

  const float* Xp = X + (long long)b * DD * NN + (long long)d0 * NN;
  const float* Cp = coef + (long long)b * NN * RR + (h << 5);

  float4 acc[8];
  #pragma unroll
  for (int q = 0; q < 8; ++q) acc[q] = make_float4(0,0,0,0);

  for (int nc = 0; nc < NN / NS_N2; nc += 64) {
    __syncthreads();
    for (int t = threadIdx.x; t < 2048; t += 256) {
      const int row = t >> 4, c4 = (t & 15) << 2;
      const float4 v = *(const float4*)&Xp[(long long)row * NN + nbeg + nc + c4];
      float* w = &xs[row * 65 + c4];
      w[0] = v.x; w[1] = v.y; w[2] = v.z; w[3] = v.w;
    }
    __syncthreads();
    const float* xrow = &xs[((dsub << 6) + lane) * 65];
    #pragma unroll 2
    for (int nn = 0; nn < 64; ++nn) {
      const float xv = xrow[nn];
      const float4* cr = (const float4*)(Cp + (long long)(nbeg + nc + nn) * RR);
      #pragma unroll
      for (int q = 0; q < 8; ++q) fma4s(acc[q], cr[q], xv);
    }
  }
  float4* op = (float4*)(n2p + (((long long)s * BSZ + b) * DD + d0 + (dsub << 6) + lane) * RR + (h << 5));
  #pragma unroll
  for (int q = 0; q < 8; ++q) op[q] = acc[q];
}

// ---------------- fused numer2-reduce + bases update
__global__ void __launch_bounds__(256) bupdate_kernel(float* __restrict__ Bw,
                                                      const float* __restrict__ n2p,
                                                      const float* __restrict__ ctc) {
  __shared__ float ct[4096];
  const int b  = blockIdx.y;
  const int d0 = blockIdx.x << 6;
  {
    const float4* src = (const float4*)(ctc + (long long)b * 4096);
    float4* dstl = (float4*)ct;
    for (int t = threadIdx.x; t < 1024; t += 256) dstl[t] = src[t];
  }
  __syncthreads();
  const int d  = d0 + (threadIdx.x >> 2);
  const int rq = (threadIdx.x & 3) << 4;

  float4 ns[4];
  #pragma unroll
  for (int j = 0; j < 4; ++j) ns[j] = make_float4(0,0,0,0);
  for (int s = 0; s < NS_N2; ++s) {
    const float4* p = (const float4*)&n2p[(((long long)s * BSZ + b) * DD + d) * RR + rq];
    #pragma unroll
    for (int j = 0; j < 4; ++j) {
      ns[j].x += p[j].x; ns[j].y += p[j].y; ns[j].z += p[j].z; ns[j].w += p[j].w;
    }
  }
  const float4* brow = (const float4*)&Bw[((long long)b * DD + d) * RR];
  float4 dn[4];
  #pragma unroll
  for (int j = 0; j < 4; ++j) dn[j] = make_float4(0,0,0,0);
  for (int q = 0; q < 16; ++q) {
    const float4 b4 = brow[q];
    const float4* c0 = (const float4*)&ct[(4 * q + 0) * 64 + rq];
    const float4* c1 = (const float4*)&ct[(4 * q + 1) * 64 + rq];
    const float4* c2 = (const float4*)&ct[(4 * q + 2) * 64 + rq];
    const float4* c3 = (const float4*)&ct[(4 * q + 3) * 64 + rq];
    #pragma unroll
    for (int j = 0; j < 4; ++j) {
      fma4s(dn[j], c0[j], b4.x); fma4s(dn[j], c1[j], b4.y);
      fma4s(dn[j], c2[j], b4.z); fma4s(dn[j], c3[j], b4.w);
    }
  }
  float4* bp = (float4*)&Bw[((long long)b * DD + d) * RR + rq];
  float4 bo[4];
  #pragma unroll
  for (int j = 0; j < 4; ++j) bo[j] = bp[j];
  __syncthreads();   // all Bw reads complete before in-place writes
  #pragma unroll
  for (int j = 0; j < 4; ++j) {
    float4 o;
    o.x = bo[j].x * ns[j].x / (dn[j].x + EPS);
    o.y = bo[j].y * ns[j].y / (dn[j].y + EPS);
    o.z = bo[j].z * ns[j].z / (dn[j].z + EPS);
    o.w = bo[j].w * ns[j].w / (dn[j].w + EPS);
    bp[j] = o;
  }
}

// ---------------- out[d][n] = sum_r B[d][r]*coef[n][r], transposed LDS tiles
__global__ void __launch_bounds__(256) out_kernel(const float* __restrict__ Bw,
                                                  const float* __restrict__ coef,
                                                  float* __restrict__ out) {
  __shared__ float bt [64 * 68];   // [r][d']
  __shared__ float ctl[64 * 68];   // [r][n']
  const int n0 = blockIdx.x << 6;
  const int d0 = blockIdx.y << 6;
  const int b  = blockIdx.z;
  const int tx = threadIdx.x & 15;
  const int ty = threadIdx.x >> 4;
  for (int t = threadIdx.x; t < 1024; t += 256) {
    const int row = t >> 4, c4 = (t & 15) << 2;
    const float4 v = *(const float4*)&Bw[((long long)b * DD + d0 + row) * RR + c4];
    bt[(c4 + 0) * 68 + row] = v.x; bt[(c4 + 1) * 68 + row] = v.y;
    bt[(c4 + 2) * 68 + row] = v.z; bt[(c4 + 3) * 68 + row] = v.w;
  }
  for (int t = threadIdx.x; t < 1024; t += 256) {
    const int row = t >> 4, c4 = (t & 15) << 2;
    const float4 v = *(const float4*)&coef[((long long)b * NN + n0 + row) * RR + c4];
    ctl[(c4 + 0) * 68 + row] = v.x; ctl[(c4 + 1) * 68 + row] = v.y;
    ctl[(c4 + 2) * 68 + row] = v.z; ctl[(c4 + 3) * 68 + row] = v.w;
  }
  __syncthreads();
  float4 ai[4];
  #pragma unroll
  for (int i = 0; i < 4; ++i) ai[i] = make_float4(0,0,0,0);
  #pragma unroll 8
  for (int r = 0; r < 64; ++r) {
    const float4 bv = *(const float4*)&bt [r * 68 + (ty << 2)];
    const float4 cv = *(const float4*)&ctl[r * 68 + (tx << 2)];
    fma4s(ai[0], cv, bv.x); fma4s(ai[1], cv, bv.y);
    fma4s(ai[2], cv, bv.z); fma4s(ai[3], cv, bv.w);
  }
  #pragma unroll
  for (int i = 0; i < 4; ++i)
    *(float4*)&out[((long long)b * DD + d0 + (ty << 2) + i) * NN + n0 + (tx << 2)] = ai[i];
}

extern "C" void kernel_launch(void* const* d_in, const int* in_sizes, int n_in,
                              void* d_out, int out_size, void* d_ws, size_t ws_size,
                              hipStream_t stream) {
  const float* x        = (const float*)d_in[0];
  const float* bases_in = (const float*)d_in[1];
  float* out = (float*)d_out;
  float* ws  = (float*)d_ws;

  float* coef    = ws;                                   // 16*4096*64
  float* bases_w = coef + (long long)BSZ * NN * RR;      // 16*512*64
  float* btbp    = bases_w + (long long)BSZ * DD * RR;   // NS_B*16*4096
  float* ctcp    = btbp + (long long)NS_B * BSZ * 4096;  // NS_C*16*4096
  float* btbs    = ctcp + (long long)NS_C * BSZ * 4096;  // 16*4096
  float* ctcs    = btbs + (long long)BSZ * 4096;         // 16*4096
  float* n2p     = ctcs + (long long)BSZ * 4096;         // NS_N2*16*512*64

  hipMemcpyAsync(bases_w, bases_in, sizeof(float) * BSZ * DD * RR,
                 hipMemcpyDeviceToDevice, stream);

  const dim3 blk(256);
  coef_kernel<0><<<dim3(NN / 128, BSZ), blk, 0, stream>>>(x, bases_w, nullptr, coef);
  for (int it = 0; it < STEPS; ++it) {
    gram_kernel<<<dim3(NS_B, BSZ), blk, 0, stream>>>(bases_w, btbp, DD / (NS_B * 4),
                                                     (long long)DD * RR);
    reduce_kernel<<<dim3(BSZ), blk, 0, stream>>>(btbp, btbs, NS_B);
    coef_kernel<1><<<dim3(NN / 128, BSZ), blk, 0, stream>>>(x, bases_w, btbs, coef);
    gram_kernel<<<dim3(NS_C, BSZ), blk, 0, stream>>>(coef, ctcp, NN / (NS_C * 4),
                                                     (long long)NN * RR);
    reduce_kernel<<<dim3(BSZ), blk, 0, stream>>>(ctcp, ctcs, NS_C);
    numer2_kernel<<<dim3(DD / 128, NS_N2, BSZ), blk, 0, stream>>>(x, coef, n2p);
    bupdate_kernel<<<dim3(DD / 64, BSZ), blk, 0, stream>>>(bases_w, n2p, ctcs);
  }
  gram_kernel<<<dim3(NS_B, BSZ), blk, 0, stream>>>(bases_w, btbp, DD / (NS_B * 4),
                                                   (long long)DD * RR);
  reduce_kernel<<<dim3(BSZ), blk, 0, stream>>>(btbp, btbs, NS_B);
  coef_kernel<1><<<dim3(NN / 128, BSZ), blk, 0, stream>>>(x, bases_w, btbs, coef);
  out_kernel<<<dim3(NN / 64, DD / 64, BSZ), blk, 0, stream>>>(bases_w, coef, out);
}

// Round 4
// 2429.280 us; speedup vs baseline: 2.2152x; 2.2152x over previous
//
#include <hip/hip_runtime.h>
#include <math.h>

#define EPS 1e-6f

constexpr int BSZ = 16;    // batch * S
constexpr int DD  = 512;   // channels / S
constexpr int NN  = 4096;  // H*W
constexpr int RR  = 64;
constexpr int STEPS = 7;
constexpr int NS_B  = 8;   // BtB d-split blocks
constexpr int NS_C  = 32;  // CtC n-split blocks
constexpr int NS_N2 = 8;   // numer2 n-split partials

__device__ __forceinline__ void fma4s(float4& a, const float4& b, float s) {
  a.x = fmaf(b.x, s, a.x); a.y = fmaf(b.y, s, a.y);
  a.z = fmaf(b.z, s, a.z); a.w = fmaf(b.w, s, a.w);
}

// ---------------- numer[n][r] = sum_d x[d][n] * B[d][r]
// 64-thread (1-wave) blocks; tile 64n x 64r; 8x8 register tile per thread.
__global__ void __launch_bounds__(64) numer_kernel(const float* __restrict__ X,
                                                   const float* __restrict__ Bw,
                                                   float* __restrict__ numer) {
  __shared__ float xs[32 * 64];
  __shared__ float bs[32 * 64];
  const int b  = blockIdx.y;
  const int n0 = blockIdx.x << 6;
  const int t  = threadIdx.x;
  const int tn = t >> 3;    // n-subgroup 0..7
  const int tr = t & 7;     // r-subgroup 0..7
  const float* Xp = X  + (long long)b * DD * NN + n0;
  const float* Bp = Bw + (long long)b * DD * RR;

  float4 acc[8][2];
  #pragma unroll
  for (int i = 0; i < 8; ++i) {
    acc[i][0] = make_float4(0.f,0.f,0.f,0.f);
    acc[i][1] = make_float4(0.f,0.f,0.f,0.f);
  }

  for (int d0 = 0; d0 < DD; d0 += 32) {
    __syncthreads();
    #pragma unroll
    for (int i = 0; i < 8; ++i) {
      const int idx = t + (i << 6);              // 0..511
      const int row = idx >> 4, c4 = (idx & 15) << 2;
      *(float4*)&xs[(row << 6) + c4] = *(const float4*)&Xp[(long long)(d0 + row) * NN + c4];
      *(float4*)&bs[(row << 6) + c4] = *(const float4*)&Bp[(long long)(d0 + row) * RR + c4];
    }
    __syncthreads();
    #pragma unroll 4
    for (int dd = 0; dd < 32; ++dd) {
      const float4 xv0 = *(const float4*)&xs[(dd << 6) + (tn << 3)];
      const float4 xv1 = *(const float4*)&xs[(dd << 6) + (tn << 3) + 4];
      const float4 bv0 = *(const float4*)&bs[(dd << 6) + (tr << 3)];
      const float4 bv1 = *(const float4*)&bs[(dd << 6) + (tr << 3) + 4];
      const float xe[8] = {xv0.x, xv0.y, xv0.z, xv0.w, xv1.x, xv1.y, xv1.z, xv1.w};
      #pragma unroll
      for (int i = 0; i < 8; ++i) {
        fma4s(acc[i][0], bv0, xe[i]);
        fma4s(acc[i][1], bv1, xe[i]);
      }
    }
  }
  #pragma unroll
  for (int i = 0; i < 8; ++i) {
    float* op = numer + ((long long)b * NN + n0 + (tn << 3) + i) * RR + (tr << 3);
    *(float4*)&op[0] = acc[i][0];
    *(float4*)&op[4] = acc[i][1];
  }
}

// ---------------- coef = softmax(numer) over r
__global__ void __launch_bounds__(256) softmax_kernel(const float* __restrict__ numer,
                                                      float* __restrict__ coef) {
  const int b = blockIdx.y;
  const int n = (blockIdx.x << 8) + threadIdx.x;
  const float4* np = (const float4*)(numer + ((long long)b * NN + n) * RR);
  float4 row[16];
  #pragma unroll
  for (int q = 0; q < 16; ++q) row[q] = np[q];
  float m = -1e30f;
  #pragma unroll
  for (int q = 0; q < 16; ++q)
    m = fmaxf(m, fmaxf(fmaxf(row[q].x, row[q].y), fmaxf(row[q].z, row[q].w)));
  float ssum = 0.f;
  #pragma unroll
  for (int q = 0; q < 16; ++q) {
    row[q].x = __expf(row[q].x - m); row[q].y = __expf(row[q].y - m);
    row[q].z = __expf(row[q].z - m); row[q].w = __expf(row[q].w - m);
    ssum += row[q].x + row[q].y + row[q].z + row[q].w;
  }
  const float inv = 1.f / ssum;
  float4* cp = (float4*)(coef + ((long long)b * NN + n) * RR);
  #pragma unroll
  for (int q = 0; q < 16; ++q) {
    float4 e = row[q];
    e.x *= inv; e.y *= inv; e.z *= inv; e.w *= inv;
    cp[q] = e;
  }
}

// ---------------- coef[n][r] = cold[n][r] * numer[n][r] / (sum_k cold[n][k]*G[k][r] + eps)
// Thread owns one full row n -> no cross-thread coef hazard. G staged in LDS,
// read at wave-uniform addresses (broadcast, conflict-free).
__global__ void __launch_bounds__(256) cupdate_kernel(const float* __restrict__ numer,
                                                      const float* __restrict__ G_,
                                                      float* __restrict__ coef) {
  __shared__ float G[64 * 64];
  const int b = blockIdx.y;
  const int n = (blockIdx.x << 8) + threadIdx.x;
  {
    const float4* src = (const float4*)(G_ + (long long)b * 4096);
    #pragma unroll
    for (int i = 0; i < 4; ++i)
      ((float4*)G)[threadIdx.x + (i << 8)] = src[threadIdx.x + (i << 8)];
  }
  __syncthreads();
  float* crow = coef + ((long long)b * NN + n) * RR;
  float4 cold[16];
  #pragma unroll
  for (int q = 0; q < 16; ++q) cold[q] = ((const float4*)crow)[q];
  const float4* np = (const float4*)(numer + ((long long)b * NN + n) * RR);

  #pragma unroll
  for (int h = 0; h < 2; ++h) {
    float4 dn[8];
    #pragma unroll
    for (int j = 0; j < 8; ++j) dn[j] = make_float4(0.f,0.f,0.f,0.f);
    #pragma unroll
    for (int q = 0; q < 16; ++q) {
      const float4 c4 = cold[q];
      const float4* g0 = (const float4*)&G[((q << 2) + 0) * 64 + (h << 5)];
      const float4* g1 = (const float4*)&G[((q << 2) + 1) * 64 + (h << 5)];
      const float4* g2 = (const float4*)&G[((q << 2) + 2) * 64 + (h << 5)];
      const float4* g3 = (const float4*)&G[((q << 2) + 3) * 64 + (h << 5)];
      #pragma unroll
      for (int j = 0; j < 8; ++j) {
        fma4s(dn[j], g0[j], c4.x); fma4s(dn[j], g1[j], c4.y);
        fma4s(dn[j], g2[j], c4.z); fma4s(dn[j], g3[j], c4.w);
      }
    }
    #pragma unroll
    for (int j = 0; j < 8; ++j) {
      const float4 co = cold[(h << 3) + j];
      const float4 nu = np[(h << 3) + j];
      float4 o;
      o.x = co.x * nu.x / (dn[j].x + EPS);
      o.y = co.y * nu.y / (dn[j].y + EPS);
      o.z = co.z * nu.z / (dn[j].z + EPS);
      o.w = co.w * nu.w / (dn[j].w + EPS);
      ((float4*)crow)[(h << 3) + j] = o;
    }
  }
}

// ---------------- n2p[s][b][d][r] = sum_{n in slice} x[d][n] * coef[n][r]
// 64-thread blocks; tile 64d x 64r; x transposed into LDS (stride 68).
__global__ void __launch_bounds__(64) numer2_kernel(const float* __restrict__ X,
                                                    const float* __restrict__ coef,
                                                    float* __restrict__ n2p) {
  __shared__ float xsT[32 * 68];   // [n][d], stride 68
  __shared__ float cs[32 * 64];    // [n][r]
  const int b  = blockIdx.z;
  const int s  = blockIdx.y;
  const int d0 = blockIdx.x << 6;
  const int t  = threadIdx.x;
  const int td = t >> 3;    // d-subgroup 0..7
  const int tr = t & 7;     // r-subgroup 0..7
  const int nbeg = s * (NN / NS_N2);
  const float* Xp = X + (long long)b * DD * NN + (long long)d0 * NN + nbeg;
  const float* Cp = coef + ((long long)b * NN + nbeg) * RR;

  float4 acc[8][2];
  #pragma unroll
  for (int i = 0; i < 8; ++i) {
    acc[i][0] = make_float4(0.f,0.f,0.f,0.f);
    acc[i][1] = make_float4(0.f,0.f,0.f,0.f);
  }

  for (int nc = 0; nc < NN / NS_N2; nc += 32) {
    __syncthreads();
    #pragma unroll
    for (int i = 0; i < 8; ++i) {
      const int idx = t + (i << 6);               // 0..511
      const int dd = idx >> 3, nq = (idx & 7) << 2;   // x: 64 d-rows x 8 float4
      const float4 v = *(const float4*)&Xp[(long long)dd * NN + nc + nq];
      xsT[(nq + 0) * 68 + dd] = v.x;
      xsT[(nq + 1) * 68 + dd] = v.y;
      xsT[(nq + 2) * 68 + dd] = v.z;
      xsT[(nq + 3) * 68 + dd] = v.w;
      const int row = idx >> 4, c4 = (idx & 15) << 2; // c: 32 n-rows x 16 float4
      *(float4*)&cs[(row << 6) + c4] = *(const float4*)&Cp[(long long)(nc + row) * RR + c4];
    }
    __syncthreads();
    #pragma unroll 4
    for (int nn = 0; nn < 32; ++nn) {
      const float4 xv0 = *(const float4*)&xsT[nn * 68 + (td << 3)];
      const float4 xv1 = *(const float4*)&xsT[nn * 68 + (td << 3) + 4];
      const float4 cv0 = *(const float4*)&cs[(nn << 6) + (tr << 3)];
      const float4 cv1 = *(const float4*)&cs[(nn << 6) + (tr << 3) + 4];
      const float xe[8] = {xv0.x, xv0.y, xv0.z, xv0.w, xv1.x, xv1.y, xv1.z, xv1.w};
      #pragma unroll
      for (int i = 0; i < 8; ++i) {
        fma4s(acc[i][0], cv0, xe[i]);
        fma4s(acc[i][1], cv1, xe[i]);
      }
    }
  }
  #pragma unroll
  for (int i = 0; i < 8; ++i) {
    float* op = n2p + (((long long)s * BSZ + b) * DD + d0 + (td << 3) + i) * RR + (tr << 3);
    *(float4*)&op[0] = acc[i][0];
    *(float4*)&op[4] = acc[i][1];
  }
}

// ---------------- Gram partials: outp[split][b][k][lane] = sum_rows M[row][k]*M[row][lane]
__global__ void __launch_bounds__(256) gram_kernel(const float* __restrict__ M,
                                                   float* __restrict__ outp,
                                                   int rowsPerWave,
                                                   long long batchStride) {
  __shared__ float red[RR * RR];
  const int lane = threadIdx.x & 63;
  const int wid  = threadIdx.x >> 6;
  const int b    = blockIdx.y;
  const long long rowbase = (long long)(blockIdx.x * 4 + wid) * rowsPerWave;
  const float* Mp = M + (long long)b * batchStride + rowbase * RR;
  float acc[RR];
  #pragma unroll
  for (int k = 0; k < RR; ++k) acc[k] = 0.f;
  #pragma unroll 2
  for (int rr = 0; rr < rowsPerWave; ++rr) {
    const float v = Mp[(long long)rr * RR + lane];
    #pragma unroll
    for (int k = 0; k < RR; ++k) acc[k] = fmaf(__shfl(v, k), v, acc[k]);
  }
  for (int w = 0; w < 4; ++w) {
    if (wid == w) {
      if (w == 0) {
        #pragma unroll
        for (int k = 0; k < RR; ++k) red[k * RR + lane] = acc[k];
      } else {
        #pragma unroll
        for (int k = 0; k < RR; ++k) red[k * RR + lane] += acc[k];
      }
    }
    __syncthreads();
  }
  float* op = outp + ((long long)blockIdx.x * BSZ + b) * (RR * RR);
  for (int i = threadIdx.x; i < RR * RR; i += 256) op[i] = red[i];
}

// ---------------- sum nsplit partials of 4096 floats per batch
__global__ void __launch_bounds__(256) reduce_kernel(const float* __restrict__ src,
                                                     float* __restrict__ dst,
                                                     int nsplit) {
  const int b  = blockIdx.x;
  const int i0 = threadIdx.x * 16;
  float4 a0 = make_float4(0,0,0,0), a1 = a0, a2 = a0, a3 = a0;
  for (int s = 0; s < nsplit; ++s) {
    const float4* p = (const float4*)&src[((long long)s * BSZ + b) * 4096 + i0];
    a0.x += p[0].x; a0.y += p[0].y; a0.z += p[0].z; a0.w += p[0].w;
    a1.x += p[1].x; a1.y += p[1].y; a1.z += p[1].z; a1.w += p[1].w;
    a2.x += p[2].x; a2.y += p[2].y; a2.z += p[2].z; a2.w += p[2].w;
    a3.x += p[3].x; a3.y += p[3].y; a3.z += p[3].z; a3.w += p[3].w;
  }
  float4* o = (float4*)&dst[(long long)b * 4096 + i0];
  o[0] = a0; o[1] = a1; o[2] = a2; o[3] = a3;
}

// ---------------- fused numer2-reduce + bases update
__global__ void __launch_bounds__(256) bupdate_kernel(float* __restrict__ Bw,
                                                      const float* __restrict__ n2p,
                                                      const float* __restrict__ ctc) {
  __shared__ float ct[4096];
  const int b  = blockIdx.y;
  const int d0 = blockIdx.x << 6;
  {
    const float4* src = (const float4*)(ctc + (long long)b * 4096);
    float4* dstl = (float4*)ct;
    for (int t = threadIdx.x; t < 1024; t += 256) dstl[t] = src[t];
  }
  __syncthreads();
  const int d  = d0 + (threadIdx.x >> 2);
  const int rq = (threadIdx.x & 3) << 4;

  float4 ns[4];
  #pragma unroll
  for (int j = 0; j < 4; ++j) ns[j] = make_float4(0,0,0,0);
  for (int s = 0; s < NS_N2; ++s) {
    const float4* p = (const float4*)&n2p[(((long long)s * BSZ + b) * DD + d) * RR + rq];
    #pragma unroll
    for (int j = 0; j < 4; ++j) {
      ns[j].x += p[j].x; ns[j].y += p[j].y; ns[j].z += p[j].z; ns[j].w += p[j].w;
    }
  }
  const float4* brow = (const float4*)&Bw[((long long)b * DD + d) * RR];
  float4 dn[4];
  #pragma unroll
  for (int j = 0; j < 4; ++j) dn[j] = make_float4(0,0,0,0);
  for (int q = 0; q < 16; ++q) {
    const float4 b4 = brow[q];
    const float4* c0 = (const float4*)&ct[(4 * q + 0) * 64 + rq];
    const float4* c1 = (const float4*)&ct[(4 * q + 1) * 64 + rq];
    const float4* c2 = (const float4*)&ct[(4 * q + 2) * 64 + rq];
    const float4* c3 = (const float4*)&ct[(4 * q + 3) * 64 + rq];
    #pragma unroll
    for (int j = 0; j < 4; ++j) {
      fma4s(dn[j], c0[j], b4.x); fma4s(dn[j], c1[j], b4.y);
      fma4s(dn[j], c2[j], b4.z); fma4s(dn[j], c3[j], b4.w);
    }
  }
  float4* bp = (float4*)&Bw[((long long)b * DD + d) * RR + rq];
  float4 bo[4];
  #pragma unroll
  for (int j = 0; j < 4; ++j) bo[j] = bp[j];
  __syncthreads();   // all Bw reads complete before in-place writes
  #pragma unroll
  for (int j = 0; j < 4; ++j) {
    float4 o;
    o.x = bo[j].x * ns[j].x / (dn[j].x + EPS);
    o.y = bo[j].y * ns[j].y / (dn[j].y + EPS);
    o.z = bo[j].z * ns[j].z / (dn[j].z + EPS);
    o.w = bo[j].w * ns[j].w / (dn[j].w + EPS);
    bp[j] = o;
  }
}

// ---------------- out[d][n] = sum_r B[d][r]*coef[n][r], transposed LDS tiles
__global__ void __launch_bounds__(256) out_kernel(const float* __restrict__ Bw,
                                                  const float* __restrict__ coef,
                                                  float* __restrict__ out) {
  __shared__ float bt [64 * 68];   // [r][d']
  __shared__ float ctl[64 * 68];   // [r][n']
  const int n0 = blockIdx.x << 6;
  const int d0 = blockIdx.y << 6;
  const int b  = blockIdx.z;
  const int tx = threadIdx.x & 15;
  const int ty = threadIdx.x >> 4;
  for (int t = threadIdx.x; t < 1024; t += 256) {
    const int row = t >> 4, c4 = (t & 15) << 2;
    const float4 v = *(const float4*)&Bw[((long long)b * DD + d0 + row) * RR + c4];
    bt[(c4 + 0) * 68 + row] = v.x; bt[(c4 + 1) * 68 + row] = v.y;
    bt[(c4 + 2) * 68 + row] = v.z; bt[(c4 + 3) * 68 + row] = v.w;
  }
  for (int t = threadIdx.x; t < 1024; t += 256) {
    const int row = t >> 4, c4 = (t & 15) << 2;
    const float4 v = *(const float4*)&coef[((long long)b * NN + n0 + row) * RR + c4];
    ctl[(c4 + 0) * 68 + row] = v.x; ctl[(c4 + 1) * 68 + row] = v.y;
    ctl[(c4 + 2) * 68 + row] = v.z; ctl[(c4 + 3) * 68 + row] = v.w;
  }
  __syncthreads();
  float4 ai[4];
  #pragma unroll
  for (int i = 0; i < 4; ++i) ai[i] = make_float4(0,0,0,0);
  #pragma unroll 8
  for (int r = 0; r < 64; ++r) {
    const float4 bv = *(const float4*)&bt [r * 68 + (ty << 2)];
    const float4 cv = *(const float4*)&ctl[r * 68 + (tx << 2)];
    fma4s(ai[0], cv, bv.x); fma4s(ai[1], cv, bv.y);
    fma4s(ai[2], cv, bv.z); fma4s(ai[3], cv, bv.w);
  }
  #pragma unroll
  for (int i = 0; i < 4; ++i)
    *(float4*)&out[((long long)b * DD + d0 + (ty << 2) + i) * NN + n0 + (tx << 2)] = ai[i];
}

extern "C" void kernel_launch(void* const* d_in, const int* in_sizes, int n_in,
                              void* d_out, int out_size, void* d_ws, size_t ws_size,
                              hipStream_t stream) {
  const float* x        = (const float*)d_in[0];
  const float* bases_in = (const float*)d_in[1];
  float* out = (float*)d_out;
  float* ws  = (float*)d_ws;

  float* coef    = ws;                                   // 16*4096*64      = 4Mi
  float* bases_w = coef + (long long)BSZ * NN * RR;      // 16*512*64       = 0.5Mi
  float* btbp    = bases_w + (long long)BSZ * DD * RR;   // 8*16*4096       = 0.5Mi
  float* ctcp    = btbp + (long long)NS_B * BSZ * 4096;  // 32*16*4096      = 2Mi
  float* btbs    = ctcp + (long long)NS_C * BSZ * 4096;  // 16*4096
  float* ctcs    = btbs + (long long)BSZ * 4096;         // 16*4096
  float* numer   = ctcs + (long long)BSZ * 4096;         // 16*4096*64 = 4Mi (aliased with n2p)
  float* n2p     = numer;                                // disjoint lifetime within an iter

  hipMemcpyAsync(bases_w, bases_in, sizeof(float) * BSZ * DD * RR,
                 hipMemcpyDeviceToDevice, stream);

  const dim3 blk256(256);
  const dim3 blk64(64);

  // init: coef = softmax(x^T B)
  numer_kernel<<<dim3(NN / 64, BSZ), blk64, 0, stream>>>(x, bases_w, numer);
  softmax_kernel<<<dim3(NN / 256, BSZ), blk256, 0, stream>>>(numer, coef);

  for (int it = 0; it < STEPS; ++it) {
    gram_kernel<<<dim3(NS_B, BSZ), blk256, 0, stream>>>(bases_w, btbp, DD / (NS_B * 4),
                                                        (long long)DD * RR);
    reduce_kernel<<<dim3(BSZ), blk256, 0, stream>>>(btbp, btbs, NS_B);
    numer_kernel<<<dim3(NN / 64, BSZ), blk64, 0, stream>>>(x, bases_w, numer);
    cupdate_kernel<<<dim3(NN / 256, BSZ), blk256, 0, stream>>>(numer, btbs, coef);
    gram_kernel<<<dim3(NS_C, BSZ), blk256, 0, stream>>>(coef, ctcp, NN / (NS_C * 4),
                                                        (long long)NN * RR);
    reduce_kernel<<<dim3(BSZ), blk256, 0, stream>>>(ctcp, ctcs, NS_C);
    numer2_kernel<<<dim3(DD / 64, NS_N2, BSZ), blk64, 0, stream>>>(x, coef, n2p);
    bupdate_kernel<<<dim3(DD / 64, BSZ), blk256, 0, stream>>>(bases_w, n2p, ctcs);
  }
  // compute_coef: one extra coef update with final bases
  gram_kernel<<<dim3(NS_B, BSZ), blk256, 0, stream>>>(bases_w, btbp, DD / (NS_B * 4),
                                                      (long long)DD * RR);
  reduce_kernel<<<dim3(BSZ), blk256, 0, stream>>>(btbp, btbs, NS_B);
  numer_kernel<<<dim3(NN / 64, BSZ), blk64, 0, stream>>>(x, bases_w, numer);
  cupdate_kernel<<<dim3(NN / 256, BSZ), blk256, 0, stream>>>(numer, btbs, coef);

  out_kernel<<<dim3(NN / 64, DD / 64, BSZ), blk256, 0, stream>>>(bases_w, coef, out);
}

// Round 5
// 2396.279 us; speedup vs baseline: 2.2457x; 1.0138x over previous
//
#include <hip/hip_runtime.h>
#include <math.h>

#define EPS 1e-6f

constexpr int BSZ = 16;    // batch * S
constexpr int DD  = 512;   // channels / S
constexpr int NN  = 4096;  // H*W
constexpr int RR  = 64;
constexpr int STEPS = 7;
constexpr int NS_B  = 8;   // BtB d-split blocks
constexpr int NS_C  = 32;  // CtC n-split blocks

__device__ __forceinline__ void fma4s(float4& a, const float4& b, float s) {
  a.x = fmaf(b.x, s, a.x); a.y = fmaf(b.y, s, a.y);
  a.z = fmaf(b.z, s, a.z); a.w = fmaf(b.w, s, a.w);
}
__device__ __forceinline__ void add4(float4& a, const float4& b) {
  a.x += b.x; a.y += b.y; a.z += b.z; a.w += b.w;
}

// ---------------- fused numer + coef-update (MODE1) / + softmax (MODE0)
// Single-wave 64-thread block owns a 64n x 64r tile; thread = 8n x 8r.
// K-loop over d is register-prefetch double-buffered.
template <int MODE>
__global__ void __launch_bounds__(64) fused_coef_kernel(const float* __restrict__ X,
                                                        const float* __restrict__ Bw,
                                                        const float* __restrict__ btbp,
                                                        float* __restrict__ coef) {
  __shared__ float xs[2][2048];   // x tile dbuf; reused as G (BtB) in MODE1 tail
  __shared__ float bs[2][2048];   // B tile dbuf; reused as cold-coef tile in MODE1 tail
  const int b  = blockIdx.y;
  const int n0 = blockIdx.x << 6;
  const int t  = threadIdx.x;
  const int tn = t >> 3;    // n-subgroup 0..7 (8 rows each)
  const int tr = t & 7;     // r-subgroup 0..7 (8 cols each)
  const float* Xp = X  + (long long)b * DD * NN + n0;
  const float* Bp = Bw + (long long)b * DD * RR;

  float4 acc[8][2];
  #pragma unroll
  for (int i = 0; i < 8; ++i) {
    acc[i][0] = make_float4(0.f,0.f,0.f,0.f);
    acc[i][1] = make_float4(0.f,0.f,0.f,0.f);
  }

  float4 px[8], pb[8];
  #pragma unroll
  for (int i = 0; i < 8; ++i) {
    const int idx = t + (i << 6);
    const int row = idx >> 4, c4 = (idx & 15) << 2;
    px[i] = *(const float4*)&Xp[(long long)row * NN + c4];
    pb[i] = *(const float4*)&Bp[(long long)row * RR + c4];
  }
  #pragma unroll
  for (int i = 0; i < 8; ++i) {
    const int idx = t + (i << 6);
    const int row = idx >> 4, c4 = (idx & 15) << 2;
    *(float4*)&xs[0][(row << 6) + c4] = px[i];
    *(float4*)&bs[0][(row << 6) + c4] = pb[i];
  }
  __syncthreads();

  for (int kt = 0; kt < DD / 32; ++kt) {
    const int cur = kt & 1;
    if (kt + 1 < DD / 32) {          // prefetch next tile into regs (no wait)
      const int d1 = (kt + 1) << 5;
      #pragma unroll
      for (int i = 0; i < 8; ++i) {
        const int idx = t + (i << 6);
        const int row = idx >> 4, c4 = (idx & 15) << 2;
        px[i] = *(const float4*)&Xp[(long long)(d1 + row) * NN + c4];
        pb[i] = *(const float4*)&Bp[(long long)(d1 + row) * RR + c4];
      }
    }
    #pragma unroll 4
    for (int dd = 0; dd < 32; ++dd) {
      const float4 xv0 = *(const float4*)&xs[cur][(dd << 6) + (tn << 3)];
      const float4 xv1 = *(const float4*)&xs[cur][(dd << 6) + (tn << 3) + 4];
      const float4 bv0 = *(const float4*)&bs[cur][(dd << 6) + (tr << 3)];
      const float4 bv1 = *(const float4*)&bs[cur][(dd << 6) + (tr << 3) + 4];
      const float xe[8] = {xv0.x, xv0.y, xv0.z, xv0.w, xv1.x, xv1.y, xv1.z, xv1.w};
      #pragma unroll
      for (int i = 0; i < 8; ++i) {
        fma4s(acc[i][0], bv0, xe[i]);
        fma4s(acc[i][1], bv1, xe[i]);
      }
    }
    if (kt + 1 < DD / 32) {
      #pragma unroll
      for (int i = 0; i < 8; ++i) {
        const int idx = t + (i << 6);
        const int row = idx >> 4, c4 = (idx & 15) << 2;
        *(float4*)&xs[cur ^ 1][(row << 6) + c4] = px[i];
        *(float4*)&bs[cur ^ 1][(row << 6) + c4] = pb[i];
      }
      __syncthreads();
    }
  }

  if constexpr (MODE == 0) {
    // softmax over r: reduce across the 8 tr-lanes sharing each row
    #pragma unroll
    for (int i = 0; i < 8; ++i) {
      float4 a0 = acc[i][0], a1 = acc[i][1];
      float m = fmaxf(fmaxf(fmaxf(a0.x, a0.y), fmaxf(a0.z, a0.w)),
                      fmaxf(fmaxf(a1.x, a1.y), fmaxf(a1.z, a1.w)));
      m = fmaxf(m, __shfl_xor(m, 1));
      m = fmaxf(m, __shfl_xor(m, 2));
      m = fmaxf(m, __shfl_xor(m, 4));
      a0.x = __expf(a0.x - m); a0.y = __expf(a0.y - m);
      a0.z = __expf(a0.z - m); a0.w = __expf(a0.w - m);
      a1.x = __expf(a1.x - m); a1.y = __expf(a1.y - m);
      a1.z = __expf(a1.z - m); a1.w = __expf(a1.w - m);
      float s = a0.x + a0.y + a0.z + a0.w + a1.x + a1.y + a1.z + a1.w;
      s += __shfl_xor(s, 1); s += __shfl_xor(s, 2); s += __shfl_xor(s, 4);
      const float inv = 1.f / s;
      a0.x *= inv; a0.y *= inv; a0.z *= inv; a0.w *= inv;
      a1.x *= inv; a1.y *= inv; a1.z *= inv; a1.w *= inv;
      float* cp = coef + ((long long)b * NN + n0 + (tn << 3) + i) * RR + (tr << 3);
      *(float4*)&cp[0] = a0;
      *(float4*)&cp[4] = a1;
    }
  } else {
    // stage G = sum of BtB partials into xs-region; cold coef tile into bs-region
    float* G  = &xs[0][0];   // 4096 floats [k][r]
    float* CO = &bs[0][0];   // 4096 floats [n'][k]
    __syncthreads();
    #pragma unroll
    for (int j = 0; j < 16; ++j) {
      const int w = t + (j << 6);           // float4 index 0..1023
      float4 s = make_float4(0.f,0.f,0.f,0.f);
      #pragma unroll
      for (int sp = 0; sp < NS_B; ++sp)
        add4(s, ((const float4*)(btbp + ((long long)sp * BSZ + b) * 4096))[w]);
      ((float4*)G)[w] = s;
    }
    #pragma unroll
    for (int j = 0; j < 16; ++j) {
      const int w = t + (j << 6);
      const int row = w >> 4, c4 = (w & 15) << 2;
      ((float4*)CO)[w] = *(const float4*)&coef[((long long)b * NN + n0 + row) * RR + c4];
    }
    __syncthreads();
    float4 dn[8][2];
    #pragma unroll
    for (int i = 0; i < 8; ++i) {
      dn[i][0] = make_float4(0.f,0.f,0.f,0.f);
      dn[i][1] = make_float4(0.f,0.f,0.f,0.f);
    }
    #pragma unroll 4
    for (int kq = 0; kq < 16; ++kq) {
      float4 g0[4], g1[4];
      #pragma unroll
      for (int j = 0; j < 4; ++j) {
        g0[j] = *(const float4*)&G[((kq << 2) + j) * 64 + (tr << 3)];
        g1[j] = *(const float4*)&G[((kq << 2) + j) * 64 + (tr << 3) + 4];
      }
      #pragma unroll
      for (int i = 0; i < 8; ++i) {
        const float4 cvi = *(const float4*)&CO[((tn << 3) + i) * 64 + (kq << 2)];
        fma4s(dn[i][0], g0[0], cvi.x); fma4s(dn[i][1], g1[0], cvi.x);
        fma4s(dn[i][0], g0[1], cvi.y); fma4s(dn[i][1], g1[1], cvi.y);
        fma4s(dn[i][0], g0[2], cvi.z); fma4s(dn[i][1], g1[2], cvi.z);
        fma4s(dn[i][0], g0[3], cvi.w); fma4s(dn[i][1], g1[3], cvi.w);
      }
    }
    #pragma unroll
    for (int i = 0; i < 8; ++i) {
      const float4 c0 = *(const float4*)&CO[((tn << 3) + i) * 64 + (tr << 3)];
      const float4 c1 = *(const float4*)&CO[((tn << 3) + i) * 64 + (tr << 3) + 4];
      float4 o0, o1;
      o0.x = c0.x * acc[i][0].x / (dn[i][0].x + EPS);
      o0.y = c0.y * acc[i][0].y / (dn[i][0].y + EPS);
      o0.z = c0.z * acc[i][0].z / (dn[i][0].z + EPS);
      o0.w = c0.w * acc[i][0].w / (dn[i][0].w + EPS);
      o1.x = c1.x * acc[i][1].x / (dn[i][1].x + EPS);
      o1.y = c1.y * acc[i][1].y / (dn[i][1].y + EPS);
      o1.z = c1.z * acc[i][1].z / (dn[i][1].z + EPS);
      o1.w = c1.w * acc[i][1].w / (dn[i][1].w + EPS);
      float* cp = coef + ((long long)b * NN + n0 + (tn << 3) + i) * RR + (tr << 3);
      *(float4*)&cp[0] = o0;
      *(float4*)&cp[4] = o1;
    }
  }
}

// ---------------- n2p[s][b][d][r] = sum_{n in slice} x[d][n] * coef[n][r]
// 64-thread blocks; tile 64d x 64r; x transposed into LDS (stride 68).
__global__ void __launch_bounds__(64, 2) numer2_kernel(const float* __restrict__ X,
                                                       const float* __restrict__ coef,
                                                       float* __restrict__ n2p,
                                                       int nsl) {
  __shared__ float xsT[32 * 68];   // [n][d], stride 68
  __shared__ float cs[32 * 64];    // [n][r]
  const int b  = blockIdx.z;
  const int s  = blockIdx.y;
  const int d0 = blockIdx.x << 6;
  const int t  = threadIdx.x;
  const int td = t >> 3;    // d-subgroup 0..7
  const int tr = t & 7;     // r-subgroup 0..7
  const int nbeg = s * nsl;
  const float* Xp = X + (long long)b * DD * NN + (long long)d0 * NN + nbeg;
  const float* Cp = coef + ((long long)b * NN + nbeg) * RR;

  float4 acc[8][2];
  #pragma unroll
  for (int i = 0; i < 8; ++i) {
    acc[i][0] = make_float4(0.f,0.f,0.f,0.f);
    acc[i][1] = make_float4(0.f,0.f,0.f,0.f);
  }

  for (int nc = 0; nc < nsl; nc += 32) {
    __syncthreads();
    #pragma unroll
    for (int i = 0; i < 8; ++i) {
      const int idx = t + (i << 6);               // 0..511
      const int dd = idx >> 3, nq = (idx & 7) << 2;   // x: 64 d-rows x 8 float4
      const float4 v = *(const float4*)&Xp[(long long)dd * NN + nc + nq];
      xsT[(nq + 0) * 68 + dd] = v.x;
      xsT[(nq + 1) * 68 + dd] = v.y;
      xsT[(nq + 2) * 68 + dd] = v.z;
      xsT[(nq + 3) * 68 + dd] = v.w;
      const int row = idx >> 4, c4 = (idx & 15) << 2; // c: 32 n-rows x 16 float4
      *(float4*)&cs[(row << 6) + c4] = *(const float4*)&Cp[(long long)(nc + row) * RR + c4];
    }
    __syncthreads();
    #pragma unroll 4
    for (int nn = 0; nn < 32; ++nn) {
      const float4 xv0 = *(const float4*)&xsT[nn * 68 + (td << 3)];
      const float4 xv1 = *(const float4*)&xsT[nn * 68 + (td << 3) + 4];
      const float4 cv0 = *(const float4*)&cs[(nn << 6) + (tr << 3)];
      const float4 cv1 = *(const float4*)&cs[(nn << 6) + (tr << 3) + 4];
      const float xe[8] = {xv0.x, xv0.y, xv0.z, xv0.w, xv1.x, xv1.y, xv1.z, xv1.w};
      #pragma unroll
      for (int i = 0; i < 8; ++i) {
        fma4s(acc[i][0], cv0, xe[i]);
        fma4s(acc[i][1], cv1, xe[i]);
      }
    }
  }
  #pragma unroll
  for (int i = 0; i < 8; ++i) {
    float* op = n2p + (((long long)s * BSZ + b) * DD + d0 + (td << 3) + i) * RR + (tr << 3);
    *(float4*)&op[0] = acc[i][0];
    *(float4*)&op[4] = acc[i][1];
  }
}

// ---------------- Gram partials: outp[split][b][k][lane] = sum_rows M[row][k]*M[row][lane]
__global__ void __launch_bounds__(256) gram_kernel(const float* __restrict__ M,
                                                   float* __restrict__ outp,
                                                   int rowsPerWave,
                                                   long long batchStride) {
  __shared__ float red[RR * RR];
  const int lane = threadIdx.x & 63;
  const int wid  = threadIdx.x >> 6;
  const int b    = blockIdx.y;
  const long long rowbase = (long long)(blockIdx.x * 4 + wid) * rowsPerWave;
  const float* Mp = M + (long long)b * batchStride + rowbase * RR;
  float acc[RR];
  #pragma unroll
  for (int k = 0; k < RR; ++k) acc[k] = 0.f;
  #pragma unroll 2
  for (int rr = 0; rr < rowsPerWave; ++rr) {
    const float v = Mp[(long long)rr * RR + lane];
    #pragma unroll
    for (int k = 0; k < RR; ++k) acc[k] = fmaf(__shfl(v, k), v, acc[k]);
  }
  for (int w = 0; w < 4; ++w) {
    if (wid == w) {
      if (w == 0) {
        #pragma unroll
        for (int k = 0; k < RR; ++k) red[k * RR + lane] = acc[k];
      } else {
        #pragma unroll
        for (int k = 0; k < RR; ++k) red[k * RR + lane] += acc[k];
      }
    }
    __syncthreads();
  }
  float* op = outp + ((long long)blockIdx.x * BSZ + b) * (RR * RR);
  for (int i = threadIdx.x; i < RR * RR; i += 256) op[i] = red[i];
}

// ---------------- fused CtC-partial-sum + numer2-partial-sum + bases update
__global__ void __launch_bounds__(256) bupdate_kernel(float* __restrict__ Bw,
                                                      const float* __restrict__ n2p,
                                                      const float* __restrict__ ctcp,
                                                      int ns2) {
  __shared__ float ct[4096];
  const int b  = blockIdx.y;
  const int d0 = blockIdx.x << 6;
  #pragma unroll
  for (int i = 0; i < 4; ++i) {
    const int w = threadIdx.x + (i << 8);
    float4 s = make_float4(0.f,0.f,0.f,0.f);
    for (int sp = 0; sp < NS_C; ++sp)
      add4(s, ((const float4*)(ctcp + ((long long)sp * BSZ + b) * 4096))[w]);
    ((float4*)ct)[w] = s;
  }
  __syncthreads();
  const int d  = d0 + (threadIdx.x >> 2);
  const int rq = (threadIdx.x & 3) << 4;

  float4 ns[4];
  #pragma unroll
  for (int j = 0; j < 4; ++j) ns[j] = make_float4(0.f,0.f,0.f,0.f);
  for (int s = 0; s < ns2; ++s) {
    const float4* p = (const float4*)&n2p[(((long long)s * BSZ + b) * DD + d) * RR + rq];
    #pragma unroll
    for (int j = 0; j < 4; ++j) add4(ns[j], p[j]);
  }
  const float4* brow = (const float4*)&Bw[((long long)b * DD + d) * RR];
  float4 dn[4];
  #pragma unroll
  for (int j = 0; j < 4; ++j) dn[j] = make_float4(0.f,0.f,0.f,0.f);
  for (int q = 0; q < 16; ++q) {
    const float4 b4 = brow[q];
    const float4* c0 = (const float4*)&ct[(4 * q + 0) * 64 + rq];
    const float4* c1 = (const float4*)&ct[(4 * q + 1) * 64 + rq];
    const float4* c2 = (const float4*)&ct[(4 * q + 2) * 64 + rq];
    const float4* c3 = (const float4*)&ct[(4 * q + 3) * 64 + rq];
    #pragma unroll
    for (int j = 0; j < 4; ++j) {
      fma4s(dn[j], c0[j], b4.x); fma4s(dn[j], c1[j], b4.y);
      fma4s(dn[j], c2[j], b4.z); fma4s(dn[j], c3[j], b4.w);
    }
  }
  float4* bp = (float4*)&Bw[((long long)b * DD + d) * RR + rq];
  float4 bo[4];
  #pragma unroll
  for (int j = 0; j < 4; ++j) bo[j] = bp[j];
  __syncthreads();   // all Bw reads complete before in-place writes
  #pragma unroll
  for (int j = 0; j < 4; ++j) {
    float4 o;
    o.x = bo[j].x * ns[j].x / (dn[j].x + EPS);
    o.y = bo[j].y * ns[j].y / (dn[j].y + EPS);
    o.z = bo[j].z * ns[j].z / (dn[j].z + EPS);
    o.w = bo[j].w * ns[j].w / (dn[j].w + EPS);
    bp[j] = o;
  }
}

// ---------------- out[d][n] = sum_r B[d][r]*coef[n][r], transposed LDS tiles
__global__ void __launch_bounds__(256) out_kernel(const float* __restrict__ Bw,
                                                  const float* __restrict__ coef,
                                                  float* __restrict__ out) {
  __shared__ float bt [64 * 68];   // [r][d']
  __shared__ float ctl[64 * 68];   // [r][n']
  const int n0 = blockIdx.x << 6;
  const int d0 = blockIdx.y << 6;
  const int b  = blockIdx.z;
  const int tx = threadIdx.x & 15;
  const int ty = threadIdx.x >> 4;
  for (int t = threadIdx.x; t < 1024; t += 256) {
    const int row = t >> 4, c4 = (t & 15) << 2;
    const float4 v = *(const float4*)&Bw[((long long)b * DD + d0 + row) * RR + c4];
    bt[(c4 + 0) * 68 + row] = v.x; bt[(c4 + 1) * 68 + row] = v.y;
    bt[(c4 + 2) * 68 + row] = v.z; bt[(c4 + 3) * 68 + row] = v.w;
  }
  for (int t = threadIdx.x; t < 1024; t += 256) {
    const int row = t >> 4, c4 = (t & 15) << 2;
    const float4 v = *(const float4*)&coef[((long long)b * NN + n0 + row) * RR + c4];
    ctl[(c4 + 0) * 68 + row] = v.x; ctl[(c4 + 1) * 68 + row] = v.y;
    ctl[(c4 + 2) * 68 + row] = v.z; ctl[(c4 + 3) * 68 + row] = v.w;
  }
  __syncthreads();
  float4 ai[4];
  #pragma unroll
  for (int i = 0; i < 4; ++i) ai[i] = make_float4(0.f,0.f,0.f,0.f);
  #pragma unroll 8
  for (int r = 0; r < 64; ++r) {
    const float4 bv = *(const float4*)&bt [r * 68 + (ty << 2)];
    const float4 cv = *(const float4*)&ctl[r * 68 + (tx << 2)];
    fma4s(ai[0], cv, bv.x); fma4s(ai[1], cv, bv.y);
    fma4s(ai[2], cv, bv.z); fma4s(ai[3], cv, bv.w);
  }
  #pragma unroll
  for (int i = 0; i < 4; ++i)
    *(float4*)&out[((long long)b * DD + d0 + (ty << 2) + i) * NN + n0 + (tx << 2)] = ai[i];
}

extern "C" void kernel_launch(void* const* d_in, const int* in_sizes, int n_in,
                              void* d_out, int out_size, void* d_ws, size_t ws_size,
                              hipStream_t stream) {
  const float* x        = (const float*)d_in[0];
  const float* bases_in = (const float*)d_in[1];
  float* out = (float*)d_out;
  float* ws  = (float*)d_ws;

  float* coef    = ws;                                   // BSZ*NN*RR      = 4Mi f
  float* bases_w = coef + (long long)BSZ * NN * RR;      // BSZ*DD*RR      = 0.5Mi f
  float* btbp    = bases_w + (long long)BSZ * DD * RR;   // NS_B*BSZ*4096  = 0.5Mi f
  float* ctcp    = btbp + (long long)NS_B * BSZ * 4096;  // NS_C*BSZ*4096  = 2Mi f
  float* n2p     = ctcp + (long long)NS_C * BSZ * 4096;  // ns2*BSZ*DD*RR

  const long long baseF = (long long)BSZ * NN * RR + (long long)BSZ * DD * RR +
                          (long long)NS_B * BSZ * 4096 + (long long)NS_C * BSZ * 4096;
  int ns2 = 16;
  if ((baseF + (long long)16 * BSZ * DD * RR) * 4 > (long long)ws_size) ns2 = 8;
  const int nsl = NN / ns2;

  hipMemcpyAsync(bases_w, bases_in, sizeof(float) * BSZ * DD * RR,
                 hipMemcpyDeviceToDevice, stream);

  const dim3 blk256(256);
  const dim3 blk64(64);

  // init: coef = softmax(x^T B)
  fused_coef_kernel<0><<<dim3(NN / 64, BSZ), blk64, 0, stream>>>(x, bases_w, nullptr, coef);

  for (int it = 0; it < STEPS; ++it) {
    gram_kernel<<<dim3(NS_B, BSZ), blk256, 0, stream>>>(bases_w, btbp, DD / (NS_B * 4),
                                                        (long long)DD * RR);
    fused_coef_kernel<1><<<dim3(NN / 64, BSZ), blk64, 0, stream>>>(x, bases_w, btbp, coef);
    gram_kernel<<<dim3(NS_C, BSZ), blk256, 0, stream>>>(coef, ctcp, NN / (NS_C * 4),
                                                        (long long)NN * RR);
    numer2_kernel<<<dim3(DD / 64, ns2, BSZ), blk64, 0, stream>>>(x, coef, n2p, nsl);
    bupdate_kernel<<<dim3(DD / 64, BSZ), blk256, 0, stream>>>(bases_w, n2p, ctcp, ns2);
  }
  // compute_coef: one extra coef update with final bases
  gram_kernel<<<dim3(NS_B, BSZ), blk256, 0, stream>>>(bases_w, btbp, DD / (NS_B * 4),
                                                      (long long)DD * RR);
  fused_coef_kernel<1><<<dim3(NN / 64, BSZ), blk64, 0, stream>>>(x, bases_w, btbp, coef);

  out_kernel<<<dim3(NN / 64, DD / 64, BSZ), blk256, 0, stream>>>(bases_w, coef, out);
}

// Round 6
// 1764.953 us; speedup vs baseline: 3.0490x; 1.3577x over previous
//
#include <hip/hip_runtime.h>
#include <math.h>

#define EPS 1e-6f

constexpr int BSZ = 16;    // batch * S
constexpr int DD  = 512;   // channels / S
constexpr int NN  = 4096;  // H*W
constexpr int RR  = 64;
constexpr int STEPS = 7;
constexpr int NS_B  = 8;   // BtB d-split blocks
constexpr int NS_C  = 32;  // CtC n-split blocks
constexpr int NS_N2 = 8;   // numer2 n-split partials

__device__ __forceinline__ void fma4s(float4& a, const float4& b, float s) {
  a.x = fmaf(b.x, s, a.x); a.y = fmaf(b.y, s, a.y);
  a.z = fmaf(b.z, s, a.z); a.w = fmaf(b.w, s, a.w);
}
__device__ __forceinline__ void add4(float4& a, const float4& b) {
  a.x += b.x; a.y += b.y; a.z += b.z; a.w += b.w;
}

// async global->LDS, 16B per lane; LDS dest = uniform base + lane*16
__device__ __forceinline__ void gload16(const float* g, float* l) {
  __builtin_amdgcn_global_load_lds(
      (const __attribute__((address_space(1))) void*)g,
      (__attribute__((address_space(3))) void*)l, 16, 0, 0);
}

// ---------------- fused numer + softmax (MODE0) / + coef multiplicative update (MODE1)
// 128-thread (2-wave) block owns 64n x 64r; thread = 4n x 8r.
// K-loop double-buffered via global_load_lds (async, zero VGPR staging).
template <int MODE>
__global__ void __launch_bounds__(128) fused_coef_kernel(const float* __restrict__ X,
                                                         const float* __restrict__ Bw,
                                                         const float* __restrict__ btbp,
                                                         float* __restrict__ coef) {
  __shared__ float lds[8192];   // [2][2048] x-tiles + [2][2048] B-tiles
  const int b    = blockIdx.y;
  const int n0   = blockIdx.x << 6;
  const int t    = threadIdx.x;
  const int wid  = t >> 6;
  const int lane = t & 63;
  const int rgrp = t & 7;       // r0 = rgrp*8
  const int ngrp = t >> 3;      // 0..15, n_local = ngrp*4
  const int nl   = ngrp << 2;
  const int r0   = rgrp << 3;
  const float* Xp = X  + (long long)b * DD * NN + n0;
  const float* Bp = Bw + (long long)b * DD * RR;

  float4 acc[4][2];
  #pragma unroll
  for (int i = 0; i < 4; ++i) { acc[i][0] = make_float4(0,0,0,0); acc[i][1] = make_float4(0,0,0,0); }

  auto stage = [&](int buf, int d0) {
    float* xd = lds + (buf << 11);
    float* bd = lds + 4096 + (buf << 11);
    const int rsub = lane >> 4;          // 0..3
    const int c4   = (lane & 15) << 2;   // float col
    #pragma unroll
    for (int j = 0; j < 4; ++j) {
      const int q   = (wid << 2) + j;    // 0..7 across 2 waves
      const int row = (q << 2) + rsub;   // 0..31
      gload16(&Xp[(long long)(d0 + row) * NN + c4], xd + (q << 8));
      gload16(&Bp[(long long)(d0 + row) * RR + c4], bd + (q << 8));
    }
  };

  stage(0, 0);
  __syncthreads();
  for (int kt = 0; kt < 16; ++kt) {
    const int cur = kt & 1;
    if (kt + 1 < 16) stage(cur ^ 1, (kt + 1) << 5);
    const float* xs = lds + (cur << 11);
    const float* bs = lds + 4096 + (cur << 11);
    #pragma unroll 8
    for (int dd = 0; dd < 32; ++dd) {
      const float4 xv  = *(const float4*)&xs[(dd << 6) + nl];
      const float4 bv0 = *(const float4*)&bs[(dd << 6) + r0];
      const float4 bv1 = *(const float4*)&bs[(dd << 6) + r0 + 4];
      fma4s(acc[0][0], bv0, xv.x); fma4s(acc[0][1], bv1, xv.x);
      fma4s(acc[1][0], bv0, xv.y); fma4s(acc[1][1], bv1, xv.y);
      fma4s(acc[2][0], bv0, xv.z); fma4s(acc[2][1], bv1, xv.z);
      fma4s(acc[3][0], bv0, xv.w); fma4s(acc[3][1], bv1, xv.w);
    }
    __syncthreads();   // drains gload vmcnt; next buf ready, cur buf free
  }

  if constexpr (MODE == 0) {
    // softmax over r: reduce across the 8 rgrp lanes sharing each n-row
    #pragma unroll
    for (int i = 0; i < 4; ++i) {
      float4 a0 = acc[i][0], a1 = acc[i][1];
      float m = fmaxf(fmaxf(fmaxf(a0.x, a0.y), fmaxf(a0.z, a0.w)),
                      fmaxf(fmaxf(a1.x, a1.y), fmaxf(a1.z, a1.w)));
      m = fmaxf(m, __shfl_xor(m, 1));
      m = fmaxf(m, __shfl_xor(m, 2));
      m = fmaxf(m, __shfl_xor(m, 4));
      a0.x = __expf(a0.x - m); a0.y = __expf(a0.y - m);
      a0.z = __expf(a0.z - m); a0.w = __expf(a0.w - m);
      a1.x = __expf(a1.x - m); a1.y = __expf(a1.y - m);
      a1.z = __expf(a1.z - m); a1.w = __expf(a1.w - m);
      float s = a0.x + a0.y + a0.z + a0.w + a1.x + a1.y + a1.z + a1.w;
      s += __shfl_xor(s, 1); s += __shfl_xor(s, 2); s += __shfl_xor(s, 4);
      const float inv = 1.f / s;
      a0.x *= inv; a0.y *= inv; a0.z *= inv; a0.w *= inv;
      a1.x *= inv; a1.y *= inv; a1.z *= inv; a1.w *= inv;
      float* cp = coef + ((long long)b * NN + n0 + nl + i) * RR + r0;
      *(float4*)&cp[0] = a0;
      *(float4*)&cp[4] = a1;
    }
  } else {
    // G = sum_sp BtB partials (64x64, linear); CO = old coef tile (float4-XOR swizzled)
    float4* G4  = (float4*)lds;
    float4* CO4 = (float4*)(lds + 4096);
    #pragma unroll
    for (int j = 0; j < 8; ++j) {
      const int w = t + (j << 7);
      float4 ssum = make_float4(0,0,0,0);
      #pragma unroll
      for (int sp = 0; sp < NS_B; ++sp)
        add4(ssum, ((const float4*)(btbp + ((long long)sp * BSZ + b) * 4096))[w]);
      G4[w] = ssum;
    }
    const float4* cof4 = (const float4*)(coef + ((long long)b * NN + n0) * RR);
    #pragma unroll
    for (int j = 0; j < 8; ++j) {
      const int w = t + (j << 7);
      const int row = w >> 4, c4 = w & 15;
      CO4[(row << 4) + (c4 ^ ((row >> 2) & 7))] = cof4[w];
    }
    __syncthreads();
    const int g = ngrp & 7;
    float4 dn[4][2];
    #pragma unroll
    for (int i = 0; i < 4; ++i) { dn[i][0] = make_float4(0,0,0,0); dn[i][1] = make_float4(0,0,0,0); }
    #pragma unroll 4
    for (int kq = 0; kq < 16; ++kq) {
      float4 g0[4], g1[4];
      #pragma unroll
      for (int jj = 0; jj < 4; ++jj) {
        g0[jj] = G4[(((kq << 2) + jj) << 4) + (rgrp << 1)];
        g1[jj] = G4[(((kq << 2) + jj) << 4) + (rgrp << 1) + 1];
      }
      #pragma unroll
      for (int i = 0; i < 4; ++i) {
        const float4 cv = CO4[((nl + i) << 4) + (kq ^ g)];
        fma4s(dn[i][0], g0[0], cv.x); fma4s(dn[i][1], g1[0], cv.x);
        fma4s(dn[i][0], g0[1], cv.y); fma4s(dn[i][1], g1[1], cv.y);
        fma4s(dn[i][0], g0[2], cv.z); fma4s(dn[i][1], g1[2], cv.z);
        fma4s(dn[i][0], g0[3], cv.w); fma4s(dn[i][1], g1[3], cv.w);
      }
    }
    #pragma unroll
    for (int i = 0; i < 4; ++i) {
      const int row = nl + i;
      const float4 c0 = CO4[(row << 4) + ((rgrp << 1) ^ g)];
      const float4 c1 = CO4[(row << 4) + (((rgrp << 1) + 1) ^ g)];
      float4 o0, o1;
      o0.x = c0.x * acc[i][0].x / (dn[i][0].x + EPS);
      o0.y = c0.y * acc[i][0].y / (dn[i][0].y + EPS);
      o0.z = c0.z * acc[i][0].z / (dn[i][0].z + EPS);
      o0.w = c0.w * acc[i][0].w / (dn[i][0].w + EPS);
      o1.x = c1.x * acc[i][1].x / (dn[i][1].x + EPS);
      o1.y = c1.y * acc[i][1].y / (dn[i][1].y + EPS);
      o1.z = c1.z * acc[i][1].z / (dn[i][1].z + EPS);
      o1.w = c1.w * acc[i][1].w / (dn[i][1].w + EPS);
      float* cp = coef + ((long long)b * NN + n0 + row) * RR + r0;
      *(float4*)&cp[0] = o0;
      *(float4*)&cp[4] = o1;
    }
  }
}

// ---------------- n2p[s][b][d][r] = sum_{n in slice} x[d][n] * coef[n][r]
// 128-thread block, tile 64d x 64r, thread 4d x 8r. x staged [64][32] with
// XOR-pre-swizzled global source (linear LDS dest) -> conflict-free column reads.
__global__ void __launch_bounds__(128) numer2_kernel(const float* __restrict__ X,
                                                     const float* __restrict__ coef,
                                                     float* __restrict__ n2p) {
  __shared__ float lds[8192];
  const int b    = blockIdx.z;
  const int s    = blockIdx.y;
  const int d0   = blockIdx.x << 6;
  const int t    = threadIdx.x;
  const int wid  = t >> 6;
  const int lane = t & 63;
  const int rgrp = t & 7;
  const int dgrp = t >> 3;      // 0..15
  const int dl   = dgrp << 2;
  const int r0   = rgrp << 3;
  const int nbeg = s * (NN / NS_N2);
  const float* Xp = X + (long long)b * DD * NN + (long long)d0 * NN;
  const float* Cp = coef + (long long)b * NN * RR;

  float4 acc[4][2];
  #pragma unroll
  for (int i = 0; i < 4; ++i) { acc[i][0] = make_float4(0,0,0,0); acc[i][1] = make_float4(0,0,0,0); }

  auto stage = [&](int buf, int nb) {
    float* xd = lds + (buf << 11);          // [64][32]
    float* cd = lds + 4096 + (buf << 11);   // [32][64]
    {
      const int rsub = lane >> 3, c4 = lane & 7;
      #pragma unroll
      for (int j = 0; j < 4; ++j) {
        const int q   = (wid << 2) + j;      // 0..7
        const int row = (q << 3) + rsub;     // 0..63
        const int sc  = (c4 ^ ((row >> 2) & 7)) << 2;   // pre-swizzled source col
        gload16(&Xp[(long long)row * NN + nb + sc], xd + (q << 8));
      }
    }
    {
      const int rsub = lane >> 4, c4 = (lane & 15) << 2;
      #pragma unroll
      for (int j = 0; j < 4; ++j) {
        const int q   = (wid << 2) + j;
        const int row = (q << 2) + rsub;     // 0..31
        gload16(&Cp[(long long)(nb + row) * RR + c4], cd + (q << 8));
      }
    }
  };

  stage(0, nbeg);
  __syncthreads();
  const int g = dgrp & 7;
  for (int kt = 0; kt < (NN / NS_N2) / 32; ++kt) {
    const int cur = kt & 1;
    if (kt + 1 < (NN / NS_N2) / 32) stage(cur ^ 1, nbeg + ((kt + 1) << 5));
    const float* xs = lds + (cur << 11);
    const float* cs = lds + 4096 + (cur << 11);
    #pragma unroll 8
    for (int nn = 0; nn < 32; ++nn) {
      const int col = ((((nn >> 2) ^ g) << 2) + (nn & 3));
      float xe[4];
      #pragma unroll
      for (int i = 0; i < 4; ++i) xe[i] = xs[((dl + i) << 5) + col];
      const float4 cv0 = *(const float4*)&cs[(nn << 6) + r0];
      const float4 cv1 = *(const float4*)&cs[(nn << 6) + r0 + 4];
      #pragma unroll
      for (int i = 0; i < 4; ++i) {
        fma4s(acc[i][0], cv0, xe[i]);
        fma4s(acc[i][1], cv1, xe[i]);
      }
    }
    __syncthreads();
  }
  #pragma unroll
  for (int i = 0; i < 4; ++i) {
    float* op = n2p + (((long long)s * BSZ + b) * DD + d0 + dl + i) * RR + r0;
    *(float4*)&op[0] = acc[i][0];
    *(float4*)&op[4] = acc[i][1];
  }
}

// ---------------- Gram partials: outp[split][b][k][lane] = sum_rows M[row][k]*M[row][lane]
__global__ void __launch_bounds__(256) gram_kernel(const float* __restrict__ M,
                                                   float* __restrict__ outp,
                                                   int rowsPerWave,
                                                   long long batchStride) {
  __shared__ float red[RR * RR];
  const int lane = threadIdx.x & 63;
  const int wid  = threadIdx.x >> 6;
  const int b    = blockIdx.y;
  const long long rowbase = (long long)(blockIdx.x * 4 + wid) * rowsPerWave;
  const float* Mp = M + (long long)b * batchStride + rowbase * RR;
  float acc[RR];
  #pragma unroll
  for (int k = 0; k < RR; ++k) acc[k] = 0.f;
  #pragma unroll 2
  for (int rr = 0; rr < rowsPerWave; ++rr) {
    const float v = Mp[(long long)rr * RR + lane];
    #pragma unroll
    for (int k = 0; k < RR; ++k) acc[k] = fmaf(__shfl(v, k), v, acc[k]);
  }
  for (int w = 0; w < 4; ++w) {
    if (wid == w) {
      if (w == 0) {
        #pragma unroll
        for (int k = 0; k < RR; ++k) red[k * RR + lane] = acc[k];
      } else {
        #pragma unroll
        for (int k = 0; k < RR; ++k) red[k * RR + lane] += acc[k];
      }
    }
    __syncthreads();
  }
  float* op = outp + ((long long)blockIdx.x * BSZ + b) * (RR * RR);
  for (int i = threadIdx.x; i < RR * RR; i += 256) op[i] = red[i];
}

// ---------------- fused CtC-partial-sum + numer2-partial-sum + bases update
__global__ void __launch_bounds__(256) bupdate_kernel(float* __restrict__ Bw,
                                                      const float* __restrict__ n2p,
                                                      const float* __restrict__ ctcp,
                                                      int ns2) {
  __shared__ float ct[4096];
  const int b  = blockIdx.y;
  const int d0 = blockIdx.x << 6;
  #pragma unroll
  for (int i = 0; i < 4; ++i) {
    const int w = threadIdx.x + (i << 8);
    float4 s = make_float4(0.f,0.f,0.f,0.f);
    for (int sp = 0; sp < NS_C; ++sp)
      add4(s, ((const float4*)(ctcp + ((long long)sp * BSZ + b) * 4096))[w]);
    ((float4*)ct)[w] = s;
  }
  __syncthreads();
  const int d  = d0 + (threadIdx.x >> 2);
  const int rq = (threadIdx.x & 3) << 4;

  float4 ns[4];
  #pragma unroll
  for (int j = 0; j < 4; ++j) ns[j] = make_float4(0.f,0.f,0.f,0.f);
  for (int s = 0; s < ns2; ++s) {
    const float4* p = (const float4*)&n2p[(((long long)s * BSZ + b) * DD + d) * RR + rq];
    #pragma unroll
    for (int j = 0; j < 4; ++j) add4(ns[j], p[j]);
  }
  const float4* brow = (const float4*)&Bw[((long long)b * DD + d) * RR];
  float4 dn[4];
  #pragma unroll
  for (int j = 0; j < 4; ++j) dn[j] = make_float4(0.f,0.f,0.f,0.f);
  for (int q = 0; q < 16; ++q) {
    const float4 b4 = brow[q];
    const float4* c0 = (const float4*)&ct[(4 * q + 0) * 64 + rq];
    const float4* c1 = (const float4*)&ct[(4 * q + 1) * 64 + rq];
    const float4* c2 = (const float4*)&ct[(4 * q + 2) * 64 + rq];
    const float4* c3 = (const float4*)&ct[(4 * q + 3) * 64 + rq];
    #pragma unroll
    for (int j = 0; j < 4; ++j) {
      fma4s(dn[j], c0[j], b4.x); fma4s(dn[j], c1[j], b4.y);
      fma4s(dn[j], c2[j], b4.z); fma4s(dn[j], c3[j], b4.w);
    }
  }
  float4* bp = (float4*)&Bw[((long long)b * DD + d) * RR + rq];
  float4 bo[4];
  #pragma unroll
  for (int j = 0; j < 4; ++j) bo[j] = bp[j];
  __syncthreads();   // all Bw reads complete before in-place writes
  #pragma unroll
  for (int j = 0; j < 4; ++j) {
    float4 o;
    o.x = bo[j].x * ns[j].x / (dn[j].x + EPS);
    o.y = bo[j].y * ns[j].y / (dn[j].y + EPS);
    o.z = bo[j].z * ns[j].z / (dn[j].z + EPS);
    o.w = bo[j].w * ns[j].w / (dn[j].w + EPS);
    bp[j] = o;
  }
}

// ---------------- out[d][n] = sum_r B[d][r]*coef[n][r], transposed LDS tiles
__global__ void __launch_bounds__(256) out_kernel(const float* __restrict__ Bw,
                                                  const float* __restrict__ coef,
                                                  float* __restrict__ out) {
  __shared__ float bt [64 * 68];   // [r][d']
  __shared__ float ctl[64 * 68];   // [r][n']
  const int n0 = blockIdx.x << 6;
  const int d0 = blockIdx.y << 6;
  const int b  = blockIdx.z;
  const int tx = threadIdx.x & 15;
  const int ty = threadIdx.x >> 4;
  for (int t = threadIdx.x; t < 1024; t += 256) {
    const int row = t >> 4, c4 = (t & 15) << 2;
    const float4 v = *(const float4*)&Bw[((long long)b * DD + d0 + row) * RR + c4];
    bt[(c4 + 0) * 68 + row] = v.x; bt[(c4 + 1) * 68 + row] = v.y;
    bt[(c4 + 2) * 68 + row] = v.z; bt[(c4 + 3) * 68 + row] = v.w;
  }
  for (int t = threadIdx.x; t < 1024; t += 256) {
    const int row = t >> 4, c4 = (t & 15) << 2;
    const float4 v = *(const float4*)&coef[((long long)b * NN + n0 + row) * RR + c4];
    ctl[(c4 + 0) * 68 + row] = v.x; ctl[(c4 + 1) * 68 + row] = v.y;
    ctl[(c4 + 2) * 68 + row] = v.z; ctl[(c4 + 3) * 68 + row] = v.w;
  }
  __syncthreads();
  float4 ai[4];
  #pragma unroll
  for (int i = 0; i < 4; ++i) ai[i] = make_float4(0.f,0.f,0.f,0.f);
  #pragma unroll 8
  for (int r = 0; r < 64; ++r) {
    const float4 bv = *(const float4*)&bt [r * 68 + (ty << 2)];
    const float4 cv = *(const float4*)&ctl[r * 68 + (tx << 2)];
    fma4s(ai[0], cv, bv.x); fma4s(ai[1], cv, bv.y);
    fma4s(ai[2], cv, bv.z); fma4s(ai[3], cv, bv.w);
  }
  #pragma unroll
  for (int i = 0; i < 4; ++i)
    *(float4*)&out[((long long)b * DD + d0 + (ty << 2) + i) * NN + n0 + (tx << 2)] = ai[i];
}

extern "C" void kernel_launch(void* const* d_in, const int* in_sizes, int n_in,
                              void* d_out, int out_size, void* d_ws, size_t ws_size,
                              hipStream_t stream) {
  const float* x        = (const float*)d_in[0];
  const float* bases_in = (const float*)d_in[1];
  float* out = (float*)d_out;
  float* ws  = (float*)d_ws;

  float* coef    = ws;                                   // BSZ*NN*RR
  float* bases_w = coef + (long long)BSZ * NN * RR;      // BSZ*DD*RR
  float* btbp    = bases_w + (long long)BSZ * DD * RR;   // NS_B*BSZ*4096
  float* ctcp    = btbp + (long long)NS_B * BSZ * 4096;  // NS_C*BSZ*4096
  float* n2p     = ctcp + (long long)NS_C * BSZ * 4096;  // NS_N2*BSZ*DD*RR

  hipMemcpyAsync(bases_w, bases_in, sizeof(float) * BSZ * DD * RR,
                 hipMemcpyDeviceToDevice, stream);

  const dim3 blk256(256);
  const dim3 blk128(128);

  // init: coef = softmax(x^T B)
  fused_coef_kernel<0><<<dim3(NN / 64, BSZ), blk128, 0, stream>>>(x, bases_w, nullptr, coef);

  for (int it = 0; it < STEPS; ++it) {
    gram_kernel<<<dim3(NS_B, BSZ), blk256, 0, stream>>>(bases_w, btbp, DD / (NS_B * 4),
                                                        (long long)DD * RR);
    fused_coef_kernel<1><<<dim3(NN / 64, BSZ), blk128, 0, stream>>>(x, bases_w, btbp, coef);
    gram_kernel<<<dim3(NS_C, BSZ), blk256, 0, stream>>>(coef, ctcp, NN / (NS_C * 4),
                                                        (long long)NN * RR);
    numer2_kernel<<<dim3(DD / 64, NS_N2, BSZ), blk128, 0, stream>>>(x, coef, n2p);
    bupdate_kernel<<<dim3(DD / 64, BSZ), blk256, 0, stream>>>(bases_w, n2p, ctcp, NS_N2);
  }
  // compute_coef: one extra coef update with final bases
  gram_kernel<<<dim3(NS_B, BSZ), blk256, 0, stream>>>(bases_w, btbp, DD / (NS_B * 4),
                                                      (long long)DD * RR);
  fused_coef_kernel<1><<<dim3(NN / 64, BSZ), blk128, 0, stream>>>(x, bases_w, btbp, coef);

  out_kernel<<<dim3(NN / 64, DD / 64, BSZ), blk256, 0, stream>>>(bases_w, coef, out);
}

// Round 7
// 1594.019 us; speedup vs baseline: 3.3760x; 1.1072x over previous
//
#include <hip/hip_runtime.h>
#include <math.h>

#define EPS 1e-6f

constexpr int BSZ = 16;    // batch * S
constexpr int DD  = 512;   // channels / S
constexpr int NN  = 4096;  // H*W
constexpr int RR  = 64;
constexpr int STEPS = 7;
constexpr int NS_B  = 8;   // BtB d-split blocks
constexpr int NS_C  = 32;  // CtC n-split blocks
constexpr int NS_N2 = 8;   // numer2 n-split partials

typedef __attribute__((ext_vector_type(8))) short short8;
typedef __attribute__((ext_vector_type(8))) unsigned short ushort8;
typedef __attribute__((ext_vector_type(4))) float f32x4;

__device__ __forceinline__ void fma4s(float4& a, const float4& b, float s) {
  a.x = fmaf(b.x, s, a.x); a.y = fmaf(b.y, s, a.y);
  a.z = fmaf(b.z, s, a.z); a.w = fmaf(b.w, s, a.w);
}
__device__ __forceinline__ void add4(float4& a, const float4& b) {
  a.x += b.x; a.y += b.y; a.z += b.z; a.w += b.w;
}
__device__ __forceinline__ unsigned short f2bf(float f) {
  unsigned u = __float_as_uint(f);
  return (unsigned short)((u + 0x7FFFu + ((u >> 16) & 1u)) >> 16);
}
__device__ __forceinline__ float bf2f(unsigned short h) {
  return __uint_as_float(((unsigned)h) << 16);
}
__device__ __forceinline__ f32x4 mfma16(short8 a, short8 b, f32x4 c) {
  return __builtin_amdgcn_mfma_f32_16x16x32_bf16(a, b, c, 0, 0, 0);
}

// async global->LDS, 16B per lane (fallback path)
__device__ __forceinline__ void gload16(const float* g, float* l) {
  __builtin_amdgcn_global_load_lds(
      (const __attribute__((address_space(1))) void*)g,
      (__attribute__((address_space(3))) void*)l, 16, 0, 0);
}

// ================= transpose + fp32->bf16 convert (hi, optional lo residual)
// src fp32 [b][R][C] -> dst bf16 [b][C][R]
template <bool LO>
__global__ void __launch_bounds__(256) tcvt_kernel(const float* __restrict__ src,
                                                   unsigned short* __restrict__ dh,
                                                   unsigned short* __restrict__ dl,
                                                   int R, int C) {
  __shared__ float tile[64][68];
  const int b = blockIdx.z, c0 = blockIdx.x << 6, r0 = blockIdx.y << 6;
  const float* sp = src + (long long)b * R * C;
  const int t = threadIdx.x;
  #pragma unroll
  for (int i = 0; i < 4; ++i) {
    const int idx = t + (i << 8);
    const int row = idx >> 4, c4 = (idx & 15) << 2;
    *(float4*)&tile[row][c4] = *(const float4*)&sp[(long long)(r0 + row) * C + c0 + c4];
  }
  __syncthreads();
  const int orow = t >> 2, och = (t & 3) << 4;
  ushort8 h0, h1, l0, l1;
  #pragma unroll
  for (int j = 0; j < 8; ++j) {
    const float v = tile[och + j][orow];
    const unsigned short h = f2bf(v);
    h0[j] = h;
    if (LO) l0[j] = f2bf(v - bf2f(h));
  }
  #pragma unroll
  for (int j = 0; j < 8; ++j) {
    const float v = tile[och + 8 + j][orow];
    const unsigned short h = f2bf(v);
    h1[j] = h;
    if (LO) l1[j] = f2bf(v - bf2f(h));
  }
  const long long ob = ((long long)b * C + c0 + orow) * R + r0 + och;
  *(ushort8*)&dh[ob] = h0;
  *(ushort8*)&dh[ob + 8] = h1;
  if (LO) { *(ushort8*)&dl[ob] = l0; *(ushort8*)&dl[ob + 8] = l1; }
}

// ================= MFMA fused numer + softmax (MODE0) / + coef update (MODE1)
// 128 thr = 2 waves; block tile 64n x 64r; wave w: n-subtiles {2w,2w+1} x 4 r-subtiles.
// numer = x_hi^T B~ + x_lo^T B~ via mfma_f32_16x16x32_bf16; frags direct from global.
template <int MODE>
__global__ void __launch_bounds__(128) fused_mfma_kernel(const unsigned short* __restrict__ xbTh,
                                                         const unsigned short* __restrict__ xbTl,
                                                         const unsigned short* __restrict__ BbT,
                                                         const float* __restrict__ btbp,
                                                         float* __restrict__ coef) {
  __shared__ float ldsp[(MODE == 1) ? 12352 : 4160];
  float* nlds = ldsp;                 // numer tile [64][65]
  const int b  = blockIdx.y;
  const int n0 = blockIdx.x << 6;
  const int t  = threadIdx.x;
  const int w  = t >> 6;
  const int l  = t & 63;
  const int row16 = l & 15;
  const int koff  = (l >> 4) << 3;

  const unsigned short* aph = xbTh + ((long long)b * NN + n0 + w * 32 + row16) * DD + koff;
  const unsigned short* apl = xbTl + ((long long)b * NN + n0 + w * 32 + row16) * DD + koff;
  const unsigned short* bpt = BbT  + ((long long)b * RR + row16) * DD + koff;

  f32x4 acc[2][4];
  #pragma unroll
  for (int s = 0; s < 2; ++s)
    #pragma unroll
    for (int r = 0; r < 4; ++r) acc[s][r] = (f32x4){0.f, 0.f, 0.f, 0.f};

  #pragma unroll
  for (int kt = 0; kt < 16; ++kt) {
    const int ko = kt << 5;
    short8 ah[2], al[2], bf[4];
    #pragma unroll
    for (int s = 0; s < 2; ++s) {
      ah[s] = *(const short8*)&aph[s * 16 * DD + ko];
      al[s] = *(const short8*)&apl[s * 16 * DD + ko];
    }
    #pragma unroll
    for (int r = 0; r < 4; ++r) bf[r] = *(const short8*)&bpt[r * 16 * DD + ko];
    #pragma unroll
    for (int s = 0; s < 2; ++s)
      #pragma unroll
      for (int r = 0; r < 4; ++r) {
        acc[s][r] = mfma16(ah[s], bf[r], acc[s][r]);
        acc[s][r] = mfma16(al[s], bf[r], acc[s][r]);
      }
  }

  // write numer tile to LDS (D-frag layout: row = (l>>4)*4+j, col = l&15)
  #pragma unroll
  for (int s = 0; s < 2; ++s)
    #pragma unroll
    for (int r = 0; r < 4; ++r)
      #pragma unroll
      for (int j = 0; j < 4; ++j)
        nlds[(w * 32 + s * 16 + ((l >> 4) << 2) + j) * 65 + (r << 4) + row16] = acc[s][r][j];

  if constexpr (MODE == 0) {
    __syncthreads();
    if (t < 64) {
      float m = -1e30f;
      for (int k = 0; k < 64; ++k) m = fmaxf(m, nlds[t * 65 + k]);
      float ssum = 0.f;
      for (int k = 0; k < 64; ++k) {
        const float e = __expf(nlds[t * 65 + k] - m);
        nlds[t * 65 + k] = e; ssum += e;
      }
      const float inv = 1.f / ssum;
      float* cp = coef + ((long long)b * NN + n0 + t) * RR;
      for (int q = 0; q < 16; ++q) {
        float4 o;
        o.x = nlds[t * 65 + 4 * q + 0] * inv;
        o.y = nlds[t * 65 + 4 * q + 1] * inv;
        o.z = nlds[t * 65 + 4 * q + 2] * inv;
        o.w = nlds[t * 65 + 4 * q + 3] * inv;
        *(float4*)&cp[q << 2] = o;
      }
    }
  } else {
    float4* G4  = (float4*)(ldsp + 4160);
    float4* CO4 = (float4*)(ldsp + 8256);
    #pragma unroll
    for (int j = 0; j < 8; ++j) {
      const int wi = t + (j << 7);
      float4 ssum = make_float4(0.f, 0.f, 0.f, 0.f);
      #pragma unroll
      for (int sp = 0; sp < NS_B; ++sp)
        add4(ssum, ((const float4*)(btbp + ((long long)sp * BSZ + b) * 4096))[wi]);
      G4[wi] = ssum;
    }
    const float4* cof4 = (const float4*)(coef + ((long long)b * NN + n0) * RR);
    #pragma unroll
    for (int j = 0; j < 8; ++j) {
      const int wi = t + (j << 7);
      const int row = wi >> 4, c4 = wi & 15;
      CO4[(row << 4) + (c4 ^ ((row >> 2) & 7))] = cof4[wi];
    }
    __syncthreads();
    const int ngrp = t >> 3, nl = ngrp << 2;
    const int rgrp = t & 7, r0 = rgrp << 3;
    const int g = ngrp & 7;
    float4 dn[4][2];
    #pragma unroll
    for (int i = 0; i < 4; ++i) { dn[i][0] = make_float4(0,0,0,0); dn[i][1] = make_float4(0,0,0,0); }
    #pragma unroll 4
    for (int kq = 0; kq < 16; ++kq) {
      float4 g0[4], g1[4];
      #pragma unroll
      for (int jj = 0; jj < 4; ++jj) {
        g0[jj] = G4[(((kq << 2) + jj) << 4) + (rgrp << 1)];
        g1[jj] = G4[(((kq << 2) + jj) << 4) + (rgrp << 1) + 1];
      }
      #pragma unroll
      for (int i = 0; i < 4; ++i) {
        const float4 cv = CO4[((nl + i) << 4) + (kq ^ g)];
        fma4s(dn[i][0], g0[0], cv.x); fma4s(dn[i][1], g1[0], cv.x);
        fma4s(dn[i][0], g0[1], cv.y); fma4s(dn[i][1], g1[1], cv.y);
        fma4s(dn[i][0], g0[2], cv.z); fma4s(dn[i][1], g1[2], cv.z);
        fma4s(dn[i][0], g0[3], cv.w); fma4s(dn[i][1], g1[3], cv.w);
      }
    }
    #pragma unroll
    for (int i = 0; i < 4; ++i) {
      const int row = nl + i;
      const float4 c0 = CO4[(row << 4) + ((rgrp << 1) ^ g)];
      const float4 c1 = CO4[(row << 4) + (((rgrp << 1) + 1) ^ g)];
      float nu[8];
      #pragma unroll
      for (int j = 0; j < 8; ++j) nu[j] = nlds[row * 65 + r0 + j];
      float4 o0, o1;
      o0.x = c0.x * nu[0] / (dn[i][0].x + EPS);
      o0.y = c0.y * nu[1] / (dn[i][0].y + EPS);
      o0.z = c0.z * nu[2] / (dn[i][0].z + EPS);
      o0.w = c0.w * nu[3] / (dn[i][0].w + EPS);
      o1.x = c1.x * nu[4] / (dn[i][1].x + EPS);
      o1.y = c1.y * nu[5] / (dn[i][1].y + EPS);
      o1.z = c1.z * nu[6] / (dn[i][1].z + EPS);
      o1.w = c1.w * nu[7] / (dn[i][1].w + EPS);
      float* cp = coef + ((long long)b * NN + n0 + row) * RR + r0;
      *(float4*)&cp[0] = o0;
      *(float4*)&cp[4] = o1;
    }
  }
}

// ================= MFMA numer2 partials: n2p[s][b][d][r] = sum_n x[d][n]*c~[n][r]
// 128 thr = 2 waves; block tile 64d x 64r; A from fp32 x (in-register hi/lo), B from cbT.
__global__ void __launch_bounds__(128) numer2_mfma_kernel(const float* __restrict__ X,
                                                          const unsigned short* __restrict__ cbT,
                                                          float* __restrict__ n2p) {
  const int b  = blockIdx.z;
  const int s  = blockIdx.y;
  const int d0 = blockIdx.x << 6;
  const int t  = threadIdx.x;
  const int w  = t >> 6;
  const int l  = t & 63;
  const int row16 = l & 15;
  const int koff  = (l >> 4) << 3;
  const int nbeg  = s * (NN / NS_N2);

  const float* xp = X + ((long long)b * DD + d0 + w * 32 + row16) * NN + nbeg + koff;
  const unsigned short* cp = cbT + ((long long)b * RR + row16) * NN + nbeg + koff;

  f32x4 acc[2][4];
  #pragma unroll
  for (int ds = 0; ds < 2; ++ds)
    #pragma unroll
    for (int rs = 0; rs < 4; ++rs) acc[ds][rs] = (f32x4){0.f, 0.f, 0.f, 0.f};

  #pragma unroll
  for (int kt = 0; kt < 16; ++kt) {
    const int ko = kt << 5;
    short8 ah[2], al[2], bf[4];
    #pragma unroll
    for (int ds = 0; ds < 2; ++ds) {
      const float4 v0 = *(const float4*)&xp[(long long)ds * 16 * NN + ko];
      const float4 v1 = *(const float4*)&xp[(long long)ds * 16 * NN + ko + 4];
      const float ve[8] = {v0.x, v0.y, v0.z, v0.w, v1.x, v1.y, v1.z, v1.w};
      #pragma unroll
      for (int j = 0; j < 8; ++j) {
        const unsigned short h = f2bf(ve[j]);
        ah[ds][j] = (short)h;
        al[ds][j] = (short)f2bf(ve[j] - bf2f(h));
      }
    }
    #pragma unroll
    for (int rs = 0; rs < 4; ++rs) bf[rs] = *(const short8*)&cp[(long long)rs * 16 * NN + ko];
    #pragma unroll
    for (int ds = 0; ds < 2; ++ds)
      #pragma unroll
      for (int rs = 0; rs < 4; ++rs) {
        acc[ds][rs] = mfma16(ah[ds], bf[rs], acc[ds][rs]);
        acc[ds][rs] = mfma16(al[ds], bf[rs], acc[ds][rs]);
      }
  }
  float* op = n2p + (((long long)s * BSZ + b) * DD + d0 + w * 32) * RR;
  #pragma unroll
  for (int ds = 0; ds < 2; ++ds)
    #pragma unroll
    for (int rs = 0; rs < 4; ++rs)
      #pragma unroll
      for (int j = 0; j < 4; ++j)
        op[(long long)(ds * 16 + ((l >> 4) << 2) + j) * RR + (rs << 4) + row16] = acc[ds][rs][j];
}

// ================= fp32 kernels (shared + round-6 fallback) =================

template <int MODE>
__global__ void __launch_bounds__(128) fused_coef_kernel(const float* __restrict__ X,
                                                         const float* __restrict__ Bw,
                                                         const float* __restrict__ btbp,
                                                         float* __restrict__ coef) {
  __shared__ float lds[8192];
  const int b    = blockIdx.y;
  const int n0   = blockIdx.x << 6;
  const int t    = threadIdx.x;
  const int wid  = t >> 6;
  const int lane = t & 63;
  const int rgrp = t & 7;
  const int ngrp = t >> 3;
  const int nl   = ngrp << 2;
  const int r0   = rgrp << 3;
  const float* Xp = X  + (long long)b * DD * NN + n0;
  const float* Bp = Bw + (long long)b * DD * RR;

  float4 acc[4][2];
  #pragma unroll
  for (int i = 0; i < 4; ++i) { acc[i][0] = make_float4(0,0,0,0); acc[i][1] = make_float4(0,0,0,0); }

  auto stage = [&](int buf, int d0) {
    float* xd = lds + (buf << 11);
    float* bd = lds + 4096 + (buf << 11);
    const int rsub = lane >> 4;
    const int c4   = (lane & 15) << 2;
    #pragma unroll
    for (int j = 0; j < 4; ++j) {
      const int q   = (wid << 2) + j;
      const int row = (q << 2) + rsub;
      gload16(&Xp[(long long)(d0 + row) * NN + c4], xd + (q << 8));
      gload16(&Bp[(long long)(d0 + row) * RR + c4], bd + (q << 8));
    }
  };

  stage(0, 0);
  __syncthreads();
  for (int kt = 0; kt < 16; ++kt) {
    const int cur = kt & 1;
    if (kt + 1 < 16) stage(cur ^ 1, (kt + 1) << 5);
    const float* xs = lds + (cur << 11);
    const float* bs = lds + 4096 + (cur << 11);
    #pragma unroll 8
    for (int dd = 0; dd < 32; ++dd) {
      const float4 xv  = *(const float4*)&xs[(dd << 6) + nl];
      const float4 bv0 = *(const float4*)&bs[(dd << 6) + r0];
      const float4 bv1 = *(const float4*)&bs[(dd << 6) + r0 + 4];
      fma4s(acc[0][0], bv0, xv.x); fma4s(acc[0][1], bv1, xv.x);
      fma4s(acc[1][0], bv0, xv.y); fma4s(acc[1][1], bv1, xv.y);
      fma4s(acc[2][0], bv0, xv.z); fma4s(acc[2][1], bv1, xv.z);
      fma4s(acc[3][0], bv0, xv.w); fma4s(acc[3][1], bv1, xv.w);
    }
    __syncthreads();
  }

  if constexpr (MODE == 0) {
    #pragma unroll
    for (int i = 0; i < 4; ++i) {
      float4 a0 = acc[i][0], a1 = acc[i][1];
      float m = fmaxf(fmaxf(fmaxf(a0.x, a0.y), fmaxf(a0.z, a0.w)),
                      fmaxf(fmaxf(a1.x, a1.y), fmaxf(a1.z, a1.w)));
      m = fmaxf(m, __shfl_xor(m, 1));
      m = fmaxf(m, __shfl_xor(m, 2));
      m = fmaxf(m, __shfl_xor(m, 4));
      a0.x = __expf(a0.x - m); a0.y = __expf(a0.y - m);
      a0.z = __expf(a0.z - m); a0.w = __expf(a0.w - m);
      a1.x = __expf(a1.x - m); a1.y = __expf(a1.y - m);
      a1.z = __expf(a1.z - m); a1.w = __expf(a1.w - m);
      float s = a0.x + a0.y + a0.z + a0.w + a1.x + a1.y + a1.z + a1.w;
      s += __shfl_xor(s, 1); s += __shfl_xor(s, 2); s += __shfl_xor(s, 4);
      const float inv = 1.f / s;
      a0.x *= inv; a0.y *= inv; a0.z *= inv; a0.w *= inv;
      a1.x *= inv; a1.y *= inv; a1.z *= inv; a1.w *= inv;
      float* cp = coef + ((long long)b * NN + n0 + nl + i) * RR + r0;
      *(float4*)&cp[0] = a0;
      *(float4*)&cp[4] = a1;
    }
  } else {
    float4* G4  = (float4*)lds;
    float4* CO4 = (float4*)(lds + 4096);
    #pragma unroll
    for (int j = 0; j < 8; ++j) {
      const int wi = t + (j << 7);
      float4 ssum = make_float4(0,0,0,0);
      #pragma unroll
      for (int sp = 0; sp < NS_B; ++sp)
        add4(ssum, ((const float4*)(btbp + ((long long)sp * BSZ + b) * 4096))[wi]);
      G4[wi] = ssum;
    }
    const float4* cof4 = (const float4*)(coef + ((long long)b * NN + n0) * RR);
    #pragma unroll
    for (int j = 0; j < 8; ++j) {
      const int wi = t + (j << 7);
      const int row = wi >> 4, c4 = wi & 15;
      CO4[(row << 4) + (c4 ^ ((row >> 2) & 7))] = cof4[wi];
    }
    __syncthreads();
    const int g = ngrp & 7;
    float4 dn[4][2];
    #pragma unroll
    for (int i = 0; i < 4; ++i) { dn[i][0] = make_float4(0,0,0,0); dn[i][1] = make_float4(0,0,0,0); }
    #pragma unroll 4
    for (int kq = 0; kq < 16; ++kq) {
      float4 g0[4], g1[4];
      #pragma unroll
      for (int jj = 0; jj < 4; ++jj) {
        g0[jj] = G4[(((kq << 2) + jj) << 4) + (rgrp << 1)];
        g1[jj] = G4[(((kq << 2) + jj) << 4) + (rgrp << 1) + 1];
      }
      #pragma unroll
      for (int i = 0; i < 4; ++i) {
        const float4 cv = CO4[((nl + i) << 4) + (kq ^ g)];
        fma4s(dn[i][0], g0[0], cv.x); fma4s(dn[i][1], g1[0], cv.x);
        fma4s(dn[i][0], g0[1], cv.y); fma4s(dn[i][1], g1[1], cv.y);
        fma4s(dn[i][0], g0[2], cv.z); fma4s(dn[i][1], g1[2], cv.z);
        fma4s(dn[i][0], g0[3], cv.w); fma4s(dn[i][1], g1[3], cv.w);
      }
    }
    #pragma unroll
    for (int i = 0; i < 4; ++i) {
      const int row = nl + i;
      const float4 c0 = CO4[(row << 4) + ((rgrp << 1) ^ g)];
      const float4 c1 = CO4[(row << 4) + (((rgrp << 1) + 1) ^ g)];
      float4 o0, o1;
      o0.x = c0.x * acc[i][0].x / (dn[i][0].x + EPS);
      o0.y = c0.y * acc[i][0].y / (dn[i][0].y + EPS);
      o0.z = c0.z * acc[i][0].z / (dn[i][0].z + EPS);
      o0.w = c0.w * acc[i][0].w / (dn[i][0].w + EPS);
      o1.x = c1.x * acc[i][1].x / (dn[i][1].x + EPS);
      o1.y = c1.y * acc[i][1].y / (dn[i][1].y + EPS);
      o1.z = c1.z * acc[i][1].z / (dn[i][1].z + EPS);
      o1.w = c1.w * acc[i][1].w / (dn[i][1].w + EPS);
      float* cp = coef + ((long long)b * NN + n0 + row) * RR + r0;
      *(float4*)&cp[0] = o0;
      *(float4*)&cp[4] = o1;
    }
  }
}

__global__ void __launch_bounds__(128) numer2_kernel(const float* __restrict__ X,
                                                     const float* __restrict__ coef,
                                                     float* __restrict__ n2p) {
  __shared__ float lds[8192];
  const int b    = blockIdx.z;
  const int s    = blockIdx.y;
  const int d0   = blockIdx.x << 6;
  const int t    = threadIdx.x;
  const int wid  = t >> 6;
  const int lane = t & 63;
  const int rgrp = t & 7;
  const int dgrp = t >> 3;
  const int dl   = dgrp << 2;
  const int r0   = rgrp << 3;
  const int nbeg = s * (NN / NS_N2);
  const float* Xp = X + (long long)b * DD * NN + (long long)d0 * NN;
  const float* Cp = coef + (long long)b * NN * RR;

  float4 acc[4][2];
  #pragma unroll
  for (int i = 0; i < 4; ++i) { acc[i][0] = make_float4(0,0,0,0); acc[i][1] = make_float4(0,0,0,0); }

  auto stage = [&](int buf, int nb) {
    float* xd = lds + (buf << 11);
    float* cd = lds + 4096 + (buf << 11);
    {
      const int rsub = lane >> 3, c4 = lane & 7;
      #pragma unroll
      for (int j = 0; j < 4; ++j) {
        const int q   = (wid << 2) + j;
        const int row = (q << 3) + rsub;
        const int sc  = (c4 ^ ((row >> 2) & 7)) << 2;
        gload16(&Xp[(long long)row * NN + nb + sc], xd + (q << 8));
      }
    }
    {
      const int rsub = lane >> 4, c4 = (lane & 15) << 2;
      #pragma unroll
      for (int j = 0; j < 4; ++j) {
        const int q   = (wid << 2) + j;
        const int row = (q << 2) + rsub;
        gload16(&Cp[(long long)(nb + row) * RR + c4], cd + (q << 8));
      }
    }
  };

  stage(0, nbeg);
  __syncthreads();
  const int g = dgrp & 7;
  for (int kt = 0; kt < (NN / NS_N2) / 32; ++kt) {
    const int cur = kt & 1;
    if (kt + 1 < (NN / NS_N2) / 32) stage(cur ^ 1, nbeg + ((kt + 1) << 5));
    const float* xs = lds + (cur << 11);
    const float* cs = lds + 4096 + (cur << 11);
    #pragma unroll 8
    for (int nn = 0; nn < 32; ++nn) {
      const int col = ((((nn >> 2) ^ g) << 2) + (nn & 3));
      float xe[4];
      #pragma unroll
      for (int i = 0; i < 4; ++i) xe[i] = xs[((dl + i) << 5) + col];
      const float4 cv0 = *(const float4*)&cs[(nn << 6) + r0];
      const float4 cv1 = *(const float4*)&cs[(nn << 6) + r0 + 4];
      #pragma unroll
      for (int i = 0; i < 4; ++i) {
        fma4s(acc[i][0], cv0, xe[i]);
        fma4s(acc[i][1], cv1, xe[i]);
      }
    }
    __syncthreads();
  }
  #pragma unroll
  for (int i = 0; i < 4; ++i) {
    float* op = n2p + (((long long)s * BSZ + b) * DD + d0 + dl + i) * RR + r0;
    *(float4*)&op[0] = acc[i][0];
    *(float4*)&op[4] = acc[i][1];
  }
}

__global__ void __launch_bounds__(256) gram_kernel(const float* __restrict__ M,
                                                   float* __restrict__ outp,
                                                   int rowsPerWave,
                                                   long long batchStride) {
  __shared__ float red[RR * RR];
  const int lane = threadIdx.x & 63;
  const int wid  = threadIdx.x >> 6;
  const int b    = blockIdx.y;
  const long long rowbase = (long long)(blockIdx.x * 4 + wid) * rowsPerWave;
  const float* Mp = M + (long long)b * batchStride + rowbase * RR;
  float acc[RR];
  #pragma unroll
  for (int k = 0; k < RR; ++k) acc[k] = 0.f;
  #pragma unroll 2
  for (int rr = 0; rr < rowsPerWave; ++rr) {
    const float v = Mp[(long long)rr * RR + lane];
    #pragma unroll
    for (int k = 0; k < RR; ++k) acc[k] = fmaf(__shfl(v, k), v, acc[k]);
  }
  for (int w = 0; w < 4; ++w) {
    if (wid == w) {
      if (w == 0) {
        #pragma unroll
        for (int k = 0; k < RR; ++k) red[k * RR + lane] = acc[k];
      } else {
        #pragma unroll
        for (int k = 0; k < RR; ++k) red[k * RR + lane] += acc[k];
      }
    }
    __syncthreads();
  }
  float* op = outp + ((long long)blockIdx.x * BSZ + b) * (RR * RR);
  for (int i = threadIdx.x; i < RR * RR; i += 256) op[i] = red[i];
}

__global__ void __launch_bounds__(256) bupdate_kernel(float* __restrict__ Bw,
                                                      const float* __restrict__ n2p,
                                                      const float* __restrict__ ctcp,
                                                      int ns2) {
  __shared__ float ct[4096];
  const int b  = blockIdx.y;
  const int d0 = blockIdx.x << 6;
  #pragma unroll
  for (int i = 0; i < 4; ++i) {
    const int w = threadIdx.x + (i << 8);
    float4 s = make_float4(0.f, 0.f, 0.f, 0.f);
    for (int sp = 0; sp < NS_C; ++sp)
      add4(s, ((const float4*)(ctcp + ((long long)sp * BSZ + b) * 4096))[w]);
    ((float4*)ct)[w] = s;
  }
  __syncthreads();
  const int d  = d0 + (threadIdx.x >> 2);
  const int rq = (threadIdx.x & 3) << 4;

  float4 ns[4];
  #pragma unroll
  for (int j = 0; j < 4; ++j) ns[j] = make_float4(0.f, 0.f, 0.f, 0.f);
  for (int s = 0; s < ns2; ++s) {
    const float4* p = (const float4*)&n2p[(((long long)s * BSZ + b) * DD + d) * RR + rq];
    #pragma unroll
    for (int j = 0; j < 4; ++j) add4(ns[j], p[j]);
  }
  const float4* brow = (const float4*)&Bw[((long long)b * DD + d) * RR];
  float4 dn[4];
  #pragma unroll
  for (int j = 0; j < 4; ++j) dn[j] = make_float4(0.f, 0.f, 0.f, 0.f);
  for (int q = 0; q < 16; ++q) {
    const float4 b4 = brow[q];
    const float4* c0 = (const float4*)&ct[(4 * q + 0) * 64 + rq];
    const float4* c1 = (const float4*)&ct[(4 * q + 1) * 64 + rq];
    const float4* c2 = (const float4*)&ct[(4 * q + 2) * 64 + rq];
    const float4* c3 = (const float4*)&ct[(4 * q + 3) * 64 + rq];
    #pragma unroll
    for (int j = 0; j < 4; ++j) {
      fma4s(dn[j], c0[j], b4.x); fma4s(dn[j], c1[j], b4.y);
      fma4s(dn[j], c2[j], b4.z); fma4s(dn[j], c3[j], b4.w);
    }
  }
  float4* bp = (float4*)&Bw[((long long)b * DD + d) * RR + rq];
  float4 bo[4];
  #pragma unroll
  for (int j = 0; j < 4; ++j) bo[j] = bp[j];
  __syncthreads();
  #pragma unroll
  for (int j = 0; j < 4; ++j) {
    float4 o;
    o.x = bo[j].x * ns[j].x / (dn[j].x + EPS);
    o.y = bo[j].y * ns[j].y / (dn[j].y + EPS);
    o.z = bo[j].z * ns[j].z / (dn[j].z + EPS);
    o.w = bo[j].w * ns[j].w / (dn[j].w + EPS);
    bp[j] = o;
  }
}

__global__ void __launch_bounds__(256) out_kernel(const float* __restrict__ Bw,
                                                  const float* __restrict__ coef,
                                                  float* __restrict__ out) {
  __shared__ float bt [64 * 68];
  __shared__ float ctl[64 * 68];
  const int n0 = blockIdx.x << 6;
  const int d0 = blockIdx.y << 6;
  const int b  = blockIdx.z;
  const int tx = threadIdx.x & 15;
  const int ty = threadIdx.x >> 4;
  for (int t = threadIdx.x; t < 1024; t += 256) {
    const int row = t >> 4, c4 = (t & 15) << 2;
    const float4 v = *(const float4*)&Bw[((long long)b * DD + d0 + row) * RR + c4];
    bt[(c4 + 0) * 68 + row] = v.x; bt[(c4 + 1) * 68 + row] = v.y;
    bt[(c4 + 2) * 68 + row] = v.z; bt[(c4 + 3) * 68 + row] = v.w;
  }
  for (int t = threadIdx.x; t < 1024; t += 256) {
    const int row = t >> 4, c4 = (t & 15) << 2;
    const float4 v = *(const float4*)&coef[((long long)b * NN + n0 + row) * RR + c4];
    ctl[(c4 + 0) * 68 + row] = v.x; ctl[(c4 + 1) * 68 + row] = v.y;
    ctl[(c4 + 2) * 68 + row] = v.z; ctl[(c4 + 3) * 68 + row] = v.w;
  }
  __syncthreads();
  float4 ai[4];
  #pragma unroll
  for (int i = 0; i < 4; ++i) ai[i] = make_float4(0.f, 0.f, 0.f, 0.f);
  #pragma unroll 8
  for (int r = 0; r < 64; ++r) {
    const float4 bv = *(const float4*)&bt [r * 68 + (ty << 2)];
    const float4 cv = *(const float4*)&ctl[r * 68 + (tx << 2)];
    fma4s(ai[0], cv, bv.x); fma4s(ai[1], cv, bv.y);
    fma4s(ai[2], cv, bv.z); fma4s(ai[3], cv, bv.w);
  }
  #pragma unroll
  for (int i = 0; i < 4; ++i)
    *(float4*)&out[((long long)b * DD + d0 + (ty << 2) + i) * NN + n0 + (tx << 2)] = ai[i];
}

extern "C" void kernel_launch(void* const* d_in, const int* in_sizes, int n_in,
                              void* d_out, int out_size, void* d_ws, size_t ws_size,
                              hipStream_t stream) {
  const float* x        = (const float*)d_in[0];
  const float* bases_in = (const float*)d_in[1];
  float* out = (float*)d_out;
  float* ws  = (float*)d_ws;

  float* coef    = ws;
  float* bases_w = coef + (long long)BSZ * NN * RR;
  float* btbp    = bases_w + (long long)BSZ * DD * RR;
  float* ctcp    = btbp + (long long)NS_B * BSZ * 4096;
  float* n2p     = ctcp + (long long)NS_C * BSZ * 4096;
  unsigned short* xbTh = (unsigned short*)(n2p + (long long)NS_N2 * BSZ * DD * RR);
  unsigned short* xbTl = xbTh + (long long)BSZ * NN * DD;
  unsigned short* BbT  = xbTl + (long long)BSZ * NN * DD;
  unsigned short* cbT  = BbT + (long long)BSZ * RR * DD;
  const long long need = (long long)((char*)(cbT + (long long)BSZ * RR * NN) - (char*)d_ws);

  const dim3 blk256(256);
  const dim3 blk128(128);

  hipMemcpyAsync(bases_w, bases_in, sizeof(float) * BSZ * DD * RR,
                 hipMemcpyDeviceToDevice, stream);

  if ((long long)ws_size >= need) {
    // ---------- bf16-MFMA path ----------
    tcvt_kernel<true><<<dim3(NN / 64, DD / 64, BSZ), blk256, 0, stream>>>(x, xbTh, xbTl, DD, NN);
    tcvt_kernel<false><<<dim3(1, DD / 64, BSZ), blk256, 0, stream>>>(bases_w, BbT, nullptr, DD, RR);
    fused_mfma_kernel<0><<<dim3(NN / 64, BSZ), blk128, 0, stream>>>(xbTh, xbTl, BbT, nullptr, coef);

    for (int it = 0; it < STEPS; ++it) {
      tcvt_kernel<false><<<dim3(1, DD / 64, BSZ), blk256, 0, stream>>>(bases_w, BbT, nullptr, DD, RR);
      gram_kernel<<<dim3(NS_B, BSZ), blk256, 0, stream>>>(bases_w, btbp, DD / (NS_B * 4),
                                                          (long long)DD * RR);
      fused_mfma_kernel<1><<<dim3(NN / 64, BSZ), blk128, 0, stream>>>(xbTh, xbTl, BbT, btbp, coef);
      tcvt_kernel<false><<<dim3(1, NN / 64, BSZ), blk256, 0, stream>>>(coef, cbT, nullptr, NN, RR);
      gram_kernel<<<dim3(NS_C, BSZ), blk256, 0, stream>>>(coef, ctcp, NN / (NS_C * 4),
                                                          (long long)NN * RR);
      numer2_mfma_kernel<<<dim3(DD / 64, NS_N2, BSZ), blk128, 0, stream>>>(x, cbT, n2p);
      bupdate_kernel<<<dim3(DD / 64, BSZ), blk256, 0, stream>>>(bases_w, n2p, ctcp, NS_N2);
    }
    tcvt_kernel<false><<<dim3(1, DD / 64, BSZ), blk256, 0, stream>>>(bases_w, BbT, nullptr, DD, RR);
    gram_kernel<<<dim3(NS_B, BSZ), blk256, 0, stream>>>(bases_w, btbp, DD / (NS_B * 4),
                                                        (long long)DD * RR);
    fused_mfma_kernel<1><<<dim3(NN / 64, BSZ), blk128, 0, stream>>>(xbTh, xbTl, BbT, btbp, coef);
    out_kernel<<<dim3(NN / 64, DD / 64, BSZ), blk256, 0, stream>>>(bases_w, coef, out);
  } else {
    // ---------- fp32 fallback (round-6 path) ----------
    fused_coef_kernel<0><<<dim3(NN / 64, BSZ), blk128, 0, stream>>>(x, bases_w, nullptr, coef);
    for (int it = 0; it < STEPS; ++it) {
      gram_kernel<<<dim3(NS_B, BSZ), blk256, 0, stream>>>(bases_w, btbp, DD / (NS_B * 4),
                                                          (long long)DD * RR);
      fused_coef_kernel<1><<<dim3(NN / 64, BSZ), blk128, 0, stream>>>(x, bases_w, btbp, coef);
      gram_kernel<<<dim3(NS_C, BSZ), blk256, 0, stream>>>(coef, ctcp, NN / (NS_C * 4),
                                                          (long long)NN * RR);
      numer2_kernel<<<dim3(DD / 64, NS_N2, BSZ), blk128, 0, stream>>>(x, coef, n2p);
      bupdate_kernel<<<dim3(DD / 64, BSZ), blk256, 0, stream>>>(bases_w, n2p, ctcp, NS_N2);
    }
    gram_kernel<<<dim3(NS_B, BSZ), blk256, 0, stream>>>(bases_w, btbp, DD / (NS_B * 4),
                                                        (long long)DD * RR);
    fused_coef_kernel<1><<<dim3(NN / 64, BSZ), blk128, 0, stream>>>(x, bases_w, btbp, coef);
    out_kernel<<<dim3(NN / 64, DD / 64, BSZ), blk256, 0, stream>>>(bases_w, coef, out);
  }
}